// Round 2
// baseline (3663.397 us; speedup 1.0000x reference)
//
#include <hip/hip_runtime.h>
#include <hip/hip_bf16.h>

#define E 256
#define H 8
#define HD 32
#define T 768
#define B 4
#define BH 32
// segments: L=[0,300), A=[300,550), V=[550,768)

__device__ __forceinline__ float b2f(__hip_bfloat16 x) { return __bfloat162float(x); }

// dtype-agnostic scalar load: f32 ? float : bf16
__device__ __forceinline__ float ldu(const void* p, size_t i, int f32) {
    if (f32) return ((const float*)p)[i];
    return b2f(((const __hip_bfloat16*)p)[i]);
}

// ---------------------------------------------------------------------------
// Kernel 0: input dtype detection. fp32 data read as bf16 halfwords yields
// garbage exponents (|x| up to 1e38) on the mantissa halves; true bf16 N(0,1)
// stays < ~10. One thread, 256 samples.
// ---------------------------------------------------------------------------
__global__ void detect_kernel(const unsigned short* __restrict__ q,
                              int* __restrict__ flag) {
    if (threadIdx.x == 0 && blockIdx.x == 0) {
        int f32 = 0;
        for (int i = 0; i < 256; ++i) {
            unsigned int bits = ((unsigned int)q[i]) << 16;
            float v = __uint_as_float(bits);
            if (!(v == v) || fabsf(v) > 1e4f) f32 = 1;
        }
        *flag = f32;
    }
}

// ---------------------------------------------------------------------------
// Kernel 1: QKV projection. One block per (t,b) row; thread e computes q/k/v[e].
// Outputs fp32 in [bh][t][hd] layout (bh = b*H + h, e = h*32 + hd).
// ---------------------------------------------------------------------------
__global__ __launch_bounds__(256) void qkv_kernel(
    const void* query, const void* key, const void* value,
    const void* w, const void* bias, const int* __restrict__ flag,
    float* __restrict__ qws, float* __restrict__ kws, float* __restrict__ vws)
{
    int f32 = *flag;
    int bid = blockIdx.x;            // t*B + b
    int t = bid >> 2, b = bid & 3;
    int e = threadIdx.x;
    __shared__ float xq[E], xk[E], xv[E];
    xq[e] = ldu(query, (size_t)bid * E + e, f32);
    xk[e] = ldu(key,   (size_t)bid * E + e, f32);
    xv[e] = ldu(value, (size_t)bid * E + e, f32);
    __syncthreads();
    float aq = 0.f, ak = 0.f, av = 0.f;
    #pragma unroll 4
    for (int j = 0; j < E; ++j) {
        float wq = ldu(w, (size_t)e * E + j, f32);
        float wk = ldu(w, (size_t)(E + e) * E + j, f32);
        float wv = ldu(w, (size_t)(2 * E + e) * E + j, f32);
        aq += xq[j] * wq;
        ak += xk[j] * wk;
        av += xv[j] * wv;
    }
    aq = (aq + ldu(bias, e, f32)) * 0.17677669529663687f;  // HD^-0.5
    ak = ak + ldu(bias, E + e, f32);
    av = av + ldu(bias, 2 * E + e, f32);
    int h = e >> 5, hd = e & 31;
    int idx = ((b * H + h) * T + t) * HD + hd;
    qws[idx] = aq; kws[idx] = ak; vws[idx] = av;
}

// ---------------------------------------------------------------------------
// Kernel 2: fused attention core. One wave per (bh, t). Per-segment exp-sums S
// and exp-weighted V partials P; all 7 branch outputs -> stacked O (3072x1792).
// Masked rows (branch excludes this t's segment) are exactly zero.
// ---------------------------------------------------------------------------
__global__ __launch_bounds__(64) void attn_kernel(
    const float* __restrict__ qws, const float* __restrict__ kws,
    const float* __restrict__ vws, float* __restrict__ O)
{
    int t = blockIdx.x, bh = blockIdx.y;
    int lane = threadIdx.x;
    __shared__ float q_s[HD];
    __shared__ float e_buf[T];
    __shared__ float S_s[3];
    __shared__ float P_part[2][3][HD];

    if (lane < HD) q_s[lane] = qws[(bh * T + t) * HD + lane];
    __syncthreads();

    float s0 = 0.f, s1 = 0.f, s2 = 0.f;
    for (int s = lane; s < T; s += 64) {
        const float4* kp = (const float4*)(kws + (size_t)(bh * T + s) * HD);
        float sc = 0.f;
        #pragma unroll
        for (int j = 0; j < 8; ++j) {
            float4 kv = kp[j];
            sc += q_s[4 * j] * kv.x + q_s[4 * j + 1] * kv.y +
                  q_s[4 * j + 2] * kv.z + q_s[4 * j + 3] * kv.w;
        }
        float ex = __expf(sc);
        e_buf[s] = ex;
        if (s < 300) s0 += ex; else if (s < 550) s1 += ex; else s2 += ex;
    }
    #pragma unroll
    for (int off = 32; off > 0; off >>= 1) {
        s0 += __shfl_down(s0, off);
        s1 += __shfl_down(s1, off);
        s2 += __shfl_down(s2, off);
    }
    if (lane == 0) { S_s[0] = s0; S_s[1] = s1; S_s[2] = s2; }
    __syncthreads();

    int hd = lane & 31, half = lane >> 5;
    float p0 = 0.f, p1 = 0.f, p2 = 0.f;
    const float* vbase = vws + (size_t)bh * T * HD + hd;
    if (half == 0) {
        for (int s = 0;   s < 300; ++s) p0 += e_buf[s] * vbase[s * HD];
        for (int s = 300; s < 384; ++s) p1 += e_buf[s] * vbase[s * HD];
    } else {
        for (int s = 384; s < 550; ++s) p1 += e_buf[s] * vbase[s * HD];
        for (int s = 550; s < 768; ++s) p2 += e_buf[s] * vbase[s * HD];
    }
    P_part[half][0][hd] = p0;
    P_part[half][1][hd] = p1;
    P_part[half][2][hd] = p2;
    __syncthreads();

    if (lane < 32) {
        float Pv[3], Sv[3];
        Pv[0] = P_part[0][0][hd] + P_part[1][0][hd];
        Pv[1] = P_part[0][1][hd] + P_part[1][1][hd];
        Pv[2] = P_part[0][2][hd] + P_part[1][2][hd];
        Sv[0] = S_s[0]; Sv[1] = S_s[1]; Sv[2] = S_s[2];
        int g = (t < 300) ? 0 : (t < 550 ? 1 : 2);
        int b = bh >> 3, h = bh & 7;
        float* orow = O + (size_t)(t * B + b) * 1792 + h * 32 + hd;
        const int masks[7] = {7, 3, 5, 6, 1, 2, 4};  // LAV,LA,LV,AV,L,A,V
        #pragma unroll
        for (int i = 0; i < 7; ++i) {
            int m = masks[i];
            float num = 0.f, den = 0.f;
            if (m & 1) { num += Pv[0]; den += Sv[0]; }
            if (m & 2) { num += Pv[1]; den += Sv[1]; }
            if (m & 4) { num += Pv[2]; den += Sv[2]; }
            orow[i * 256] = ((m >> g) & 1) ? num / den : 0.f;
        }
    }
}

// ---------------------------------------------------------------------------
// Weight combination: D_i = (final_w @ G_i @ out_w[i])^T stacked as (1792,256).
// G_i = sum of the s_*_w 256-col blocks where branch i appears.
// ---------------------------------------------------------------------------
__device__ __forceinline__ float gsum_load(int i, int r2, int r,
                                           const void* sl, const void* sa,
                                           const void* sv, int f32)
{
    size_t base = (size_t)r2 * 1024;
    switch (i) {
        case 0: return ldu(sl, base + r, f32) + ldu(sa, base + r, f32) + ldu(sv, base + r, f32);
        case 1: return ldu(sl, base + 256 + r, f32) + ldu(sa, base + 256 + r, f32);
        case 2: return ldu(sl, base + 512 + r, f32) + ldu(sv, base + 256 + r, f32);
        case 3: return ldu(sa, base + 512 + r, f32) + ldu(sv, base + 512 + r, f32);
        case 4: return ldu(sl, base + 768 + r, f32);
        case 5: return ldu(sa, base + 768 + r, f32);
        default: return ldu(sv, base + 768 + r, f32);
    }
}

// Mtmp_i = G_i @ out_w[i]    (block = (i, r2), thread = c)
__global__ __launch_bounds__(256) void wcomb1_kernel(
    const void* sl, const void* sa, const void* sv, const void* outw,
    const int* __restrict__ flag, float* __restrict__ Mtmp)
{
    int f32 = *flag;
    int bid = blockIdx.x;
    int i = bid >> 8, r2 = bid & 255;
    int c = threadIdx.x;
    __shared__ float g[256];
    g[c] = gsum_load(i, r2, c, sl, sa, sv, f32);
    __syncthreads();
    float acc = 0.f;
    for (int r = 0; r < 256; ++r)
        acc += g[r] * ldu(outw, (size_t)i * 65536 + r * 256 + c, f32);
    Mtmp[(size_t)i * 65536 + r2 * 256 + c] = acc;
}

// Dstack[(i*256+c)][e] = (final_w @ Mtmp_i)[e][c]   (block = (i, c), thread = e)
__global__ __launch_bounds__(256) void wcomb2_kernel(
    const float* __restrict__ Mtmp, const void* finalw,
    const int* __restrict__ flag, float* __restrict__ Dstack)
{
    int f32 = *flag;
    int bid = blockIdx.x;
    int i = bid >> 8, c = bid & 255;
    int e = threadIdx.x;
    __shared__ float mcol[256];
    mcol[e] = Mtmp[(size_t)i * 65536 + e * 256 + c];
    __syncthreads();
    float acc = 0.f;
    #pragma unroll 4
    for (int j = 0; j < 256; ++j)
        acc += ldu(finalw, (size_t)e * 256 + j, f32) * mcol[j];
    Dstack[(size_t)(i * 256 + c) * 256 + e] = acc;
}

// d0 = final_b + final_w @ ((s_l_b+s_a_b+s_v_b) + sum_i G_i @ out_b[i])
__global__ __launch_bounds__(256) void bias_kernel(
    const void* sl, const void* sa, const void* sv, const void* outb,
    const void* slb, const void* sab, const void* svb,
    const void* finalw, const void* finalb, const int* __restrict__ flag,
    float* __restrict__ d0)
{
    int f32 = *flag;
    int tid = threadIdx.x;
    __shared__ float c0[256];
    float acc = ldu(slb, tid, f32) + ldu(sab, tid, f32) + ldu(svb, tid, f32);
    for (int i = 0; i < 7; ++i)
        for (int m = 0; m < 256; ++m)
            acc += ldu(outb, i * 256 + m, f32) * gsum_load(i, tid, m, sl, sa, sv, f32);
    c0[tid] = acc;
    __syncthreads();
    float d = ldu(finalb, tid, f32);
    for (int r = 0; r < 256; ++r)
        d += c0[r] * ldu(finalw, (size_t)tid * 256 + r, f32);
    d0[tid] = d;
}

// ---------------------------------------------------------------------------
// Kernel 4: result = O (3072x1792) @ Dstack (1792x256) + d0. Output dtype
// follows the detected input dtype. 64x64 tiles, 4x4 per thread, skipping
// branch K-blocks that are all-zero for this row tile's segment(s).
// ---------------------------------------------------------------------------
__global__ __launch_bounds__(256) void final_gemm_kernel(
    const float* __restrict__ O, const float* __restrict__ Dstack,
    const float* __restrict__ d0, const int* __restrict__ flag,
    void* __restrict__ outv)
{
    int f32 = *flag;
    int bx = blockIdx.x;   // col tile 0..3
    int by = blockIdx.y;   // row tile 0..47
    int tid = threadIdx.x;
    int tx = tid & 15, ty = tid >> 4;
    __shared__ float As[64][33];
    __shared__ float Bs[32][65];
    float acc[4][4] = {};

    int t0 = by * 16, t1 = t0 + 15;
    int g0 = (t0 < 300) ? 0 : (t0 < 550 ? 1 : 2);
    int g1 = (t1 < 300) ? 0 : (t1 < 550 ? 1 : 2);
    int activeset = (1 << g0) | (1 << g1);
    const int masks[7] = {7, 3, 5, 6, 1, 2, 4};
    int rowbase = by * 64, colbase = bx * 64;

    for (int i = 0; i < 7; ++i) {
        if (!(masks[i] & activeset)) continue;   // whole O block is zero
        for (int kb = 0; kb < 8; ++kb) {
            int cb = i * 256 + kb * 32;
            __syncthreads();
            #pragma unroll
            for (int l = 0; l < 8; ++l) {
                int idx = l * 256 + tid;
                int r = idx >> 5, c = idx & 31;
                As[r][c] = O[(size_t)(rowbase + r) * 1792 + cb + c];
                int kk = idx >> 6, e2 = idx & 63;
                Bs[kk][e2] = Dstack[(size_t)(cb + kk) * 256 + colbase + e2];
            }
            __syncthreads();
            #pragma unroll 8
            for (int kk = 0; kk < 32; ++kk) {
                float av[4], bv[4];
                #pragma unroll
                for (int u = 0; u < 4; ++u) av[u] = As[ty * 4 + u][kk];
                #pragma unroll
                for (int v = 0; v < 4; ++v) bv[v] = Bs[kk][tx * 4 + v];
                #pragma unroll
                for (int u = 0; u < 4; ++u)
                    #pragma unroll
                    for (int v = 0; v < 4; ++v)
                        acc[u][v] += av[u] * bv[v];
            }
        }
    }
    #pragma unroll
    for (int u = 0; u < 4; ++u)
        #pragma unroll
        for (int v = 0; v < 4; ++v) {
            int r = rowbase + ty * 4 + u, c = colbase + tx * 4 + v;
            float val = acc[u][v] + d0[c];
            if (f32) ((float*)outv)[(size_t)r * 256 + c] = val;
            else ((__hip_bfloat16*)outv)[(size_t)r * 256 + c] = __float2bfloat16(val);
        }
}

// ---------------------------------------------------------------------------
extern "C" void kernel_launch(void* const* d_in, const int* in_sizes, int n_in,
                              void* d_out, int out_size, void* d_ws, size_t ws_size,
                              hipStream_t stream) {
    const void* query     = d_in[0];
    const void* key       = d_in[1];
    const void* value     = d_in[2];
    const void* in_proj_w = d_in[3];
    const void* in_proj_b = d_in[4];
    const void* out_w     = d_in[5];
    const void* out_b     = d_in[6];
    const void* s_l_w     = d_in[7];
    const void* s_l_b     = d_in[8];
    const void* s_a_w     = d_in[9];
    const void* s_a_b     = d_in[10];
    const void* s_v_w     = d_in[11];
    const void* s_v_b     = d_in[12];
    const void* final_w   = d_in[13];
    const void* final_b   = d_in[14];

    float* ws     = (float*)d_ws;
    float* qws    = ws;                 //   786432 f
    float* kws    = ws + 786432;        //   786432 f
    float* vws    = ws + 1572864;       //   786432 f
    float* O      = ws + 2359296;       //  5505024 f (3072 x 1792)
    float* Mtmp   = ws + 7864320;       //   458752 f
    float* Dstack = ws + 8323072;       //   458752 f (1792 x 256)
    float* d0     = ws + 8781824;       //      256 f
    int*   flag   = (int*)(ws + 8782080);  // 1 int  (total ~35.1 MB)

    detect_kernel<<<1, 64, 0, stream>>>((const unsigned short*)query, flag);
    qkv_kernel<<<T * B, 256, 0, stream>>>(query, key, value, in_proj_w, in_proj_b,
                                          flag, qws, kws, vws);
    wcomb1_kernel<<<7 * 256, 256, 0, stream>>>(s_l_w, s_a_w, s_v_w, out_w, flag, Mtmp);
    attn_kernel<<<dim3(T, BH), 64, 0, stream>>>(qws, kws, vws, O);
    wcomb2_kernel<<<7 * 256, 256, 0, stream>>>(Mtmp, final_w, flag, Dstack);
    bias_kernel<<<1, 256, 0, stream>>>(s_l_w, s_a_w, s_v_w, out_b,
                                       s_l_b, s_a_b, s_v_b, final_w, final_b,
                                       flag, d0);
    final_gemm_kernel<<<dim3(4, 48), 256, 0, stream>>>(O, Dstack, d0, flag, d_out);
}

// Round 4
// 1623.417 us; speedup vs baseline: 2.2566x; 2.2566x over previous
//
#include <hip/hip_runtime.h>
#include <hip/hip_bf16.h>

#define E 256
#define H 8
#define HD 32
#define T 768
#define B 4
#define BH 32
// segments: L=[0,300), A=[300,550), V=[550,768)

__device__ __forceinline__ float b2f(__hip_bfloat16 x) { return __bfloat162float(x); }

// dtype-agnostic scalar load: f32 ? float : bf16
__device__ __forceinline__ float ldu(const void* p, size_t i, int f32) {
    if (f32) return ((const float*)p)[i];
    return b2f(((const __hip_bfloat16*)p)[i]);
}

// ---------------------------------------------------------------------------
// Kernel 0: input dtype detection (fp32 read as bf16 -> garbage exponents).
// ---------------------------------------------------------------------------
__global__ void detect_kernel(const unsigned short* __restrict__ q,
                              int* __restrict__ flag) {
    if (threadIdx.x == 0 && blockIdx.x == 0) {
        int f32 = 0;
        for (int i = 0; i < 256; ++i) {
            unsigned int bits = ((unsigned int)q[i]) << 16;
            float v = __uint_as_float(bits);
            if (!(v == v) || fabsf(v) > 1e4f) f32 = 1;
        }
        *flag = f32;
    }
}

// ---------------------------------------------------------------------------
// Kernel 1: QKV projection as a tiled GEMM.
// C(3072x768) = X @ W^T ; col sections [0,256)=q,[256,512)=k,[512,768)=v pick
// the X source. 64x64 tile, K chunked by 32, 4x4 accum per thread.
// Epilogue: +bias, q-scaling, scatter to [bh][t][hd] fp32.
// ---------------------------------------------------------------------------
__global__ __launch_bounds__(256) void qkv_gemm_kernel(
    const void* query, const void* key, const void* value,
    const void* w, const void* bias, const int* __restrict__ flag,
    float* __restrict__ qws, float* __restrict__ kws, float* __restrict__ vws)
{
    int f32 = *flag;
    int bx = blockIdx.x;              // 0..11 col tiles
    int by = blockIdx.y;              // 0..47 row tiles
    int sec = bx >> 2;                // 0=q, 1=k, 2=v
    const void* X = (sec == 0) ? query : (sec == 1) ? key : value;
    int colbase = bx * 64;            // global col in [0,768)
    int rowbase = by * 64;            // row = t*B + b
    int tid = threadIdx.x;
    int tx = tid & 15, ty = tid >> 4;
    __shared__ float As[64][33];      // X[row][k]
    __shared__ float Bs[32][65];      // W^T[k][col]
    float acc[4][4] = {};

    for (int kb = 0; kb < 8; ++kb) {
        __syncthreads();
        #pragma unroll
        for (int l = 0; l < 8; ++l) {
            int idx = l * 256 + tid;
            int r = idx >> 5, c = idx & 31;
            As[r][c] = ldu(X, (size_t)(rowbase + r) * 256 + kb * 32 + c, f32);
            int n = idx >> 5, kk = idx & 31;
            Bs[kk][n] = ldu(w, (size_t)(colbase + n) * 256 + kb * 32 + kk, f32);
        }
        __syncthreads();
        #pragma unroll 8
        for (int kk = 0; kk < 32; ++kk) {
            float av[4], bv[4];
            #pragma unroll
            for (int u = 0; u < 4; ++u) av[u] = As[ty * 4 + u][kk];
            #pragma unroll
            for (int v = 0; v < 4; ++v) bv[v] = Bs[kk][tx * 4 + v];
            #pragma unroll
            for (int u = 0; u < 4; ++u)
                #pragma unroll
                for (int v = 0; v < 4; ++v)
                    acc[u][v] += av[u] * bv[v];
        }
    }
    float* dst = (sec == 0) ? qws : (sec == 1) ? kws : vws;
    #pragma unroll
    for (int u = 0; u < 4; ++u)
        #pragma unroll
        for (int v = 0; v < 4; ++v) {
            int r = rowbase + ty * 4 + u;          // t*B + b
            int cg = colbase + tx * 4 + v;         // 0..767
            float val = acc[u][v] + ldu(bias, cg, f32);
            if (sec == 0) val *= 0.17677669529663687f;  // HD^-0.5
            int e_local = cg & 255;
            int h = e_local >> 5, hd = e_local & 31;
            int t = r >> 2, b = r & 3;
            dst[((size_t)((b * H + h) * T + t)) * HD + hd] = val;
        }
}

// ---------------------------------------------------------------------------
// Kernel 2: fused attention core. One wave per (bh, t). Per-segment exp-sums S
// and exp-weighted V partials P; all 7 branch outputs -> stacked O (3072x1792).
// ---------------------------------------------------------------------------
__global__ __launch_bounds__(64) void attn_kernel(
    const float* __restrict__ qws, const float* __restrict__ kws,
    const float* __restrict__ vws, float* __restrict__ O)
{
    int t = blockIdx.x, bh = blockIdx.y;
    int lane = threadIdx.x;
    __shared__ float q_s[HD];
    __shared__ float e_buf[T];
    __shared__ float S_s[3];
    __shared__ float P_part[2][3][HD];

    if (lane < HD) q_s[lane] = qws[(bh * T + t) * HD + lane];
    __syncthreads();

    float s0 = 0.f, s1 = 0.f, s2 = 0.f;
    for (int s = lane; s < T; s += 64) {
        const float4* kp = (const float4*)(kws + (size_t)(bh * T + s) * HD);
        float sc = 0.f;
        #pragma unroll
        for (int j = 0; j < 8; ++j) {
            float4 kv = kp[j];
            sc += q_s[4 * j] * kv.x + q_s[4 * j + 1] * kv.y +
                  q_s[4 * j + 2] * kv.z + q_s[4 * j + 3] * kv.w;
        }
        float ex = __expf(sc);
        e_buf[s] = ex;
        if (s < 300) s0 += ex; else if (s < 550) s1 += ex; else s2 += ex;
    }
    #pragma unroll
    for (int off = 32; off > 0; off >>= 1) {
        s0 += __shfl_down(s0, off);
        s1 += __shfl_down(s1, off);
        s2 += __shfl_down(s2, off);
    }
    if (lane == 0) { S_s[0] = s0; S_s[1] = s1; S_s[2] = s2; }
    __syncthreads();

    int hd = lane & 31, half = lane >> 5;
    float p0 = 0.f, p1 = 0.f, p2 = 0.f;
    const float* vbase = vws + (size_t)bh * T * HD + hd;
    if (half == 0) {
        for (int s = 0;   s < 300; ++s) p0 += e_buf[s] * vbase[s * HD];
        for (int s = 300; s < 384; ++s) p1 += e_buf[s] * vbase[s * HD];
    } else {
        for (int s = 384; s < 550; ++s) p1 += e_buf[s] * vbase[s * HD];
        for (int s = 550; s < 768; ++s) p2 += e_buf[s] * vbase[s * HD];
    }
    P_part[half][0][hd] = p0;
    P_part[half][1][hd] = p1;
    P_part[half][2][hd] = p2;
    __syncthreads();

    if (lane < 32) {
        float Pv[3], Sv[3];
        Pv[0] = P_part[0][0][hd] + P_part[1][0][hd];
        Pv[1] = P_part[0][1][hd] + P_part[1][1][hd];
        Pv[2] = P_part[0][2][hd] + P_part[1][2][hd];
        Sv[0] = S_s[0]; Sv[1] = S_s[1]; Sv[2] = S_s[2];
        int g = (t < 300) ? 0 : (t < 550 ? 1 : 2);
        int b = bh >> 3, h = bh & 7;
        float* orow = O + (size_t)(t * B + b) * 1792 + h * 32 + hd;
        const int masks[7] = {7, 3, 5, 6, 1, 2, 4};  // LAV,LA,LV,AV,L,A,V
        #pragma unroll
        for (int i = 0; i < 7; ++i) {
            int m = masks[i];
            float num = 0.f, den = 0.f;
            if (m & 1) { num += Pv[0]; den += Sv[0]; }
            if (m & 2) { num += Pv[1]; den += Sv[1]; }
            if (m & 4) { num += Pv[2]; den += Sv[2]; }
            orow[i * 256] = ((m >> g) & 1) ? num / den : 0.f;
        }
    }
}

// ---------------------------------------------------------------------------
// Weight combination: D_i = (final_w @ G_i @ out_w[i])^T stacked as (1792,256).
// ---------------------------------------------------------------------------
__device__ __forceinline__ float gsum_load(int i, int r2, int r,
                                           const void* sl, const void* sa,
                                           const void* sv, int f32)
{
    size_t base = (size_t)r2 * 1024;
    switch (i) {
        case 0: return ldu(sl, base + r, f32) + ldu(sa, base + r, f32) + ldu(sv, base + r, f32);
        case 1: return ldu(sl, base + 256 + r, f32) + ldu(sa, base + 256 + r, f32);
        case 2: return ldu(sl, base + 512 + r, f32) + ldu(sv, base + 256 + r, f32);
        case 3: return ldu(sa, base + 512 + r, f32) + ldu(sv, base + 512 + r, f32);
        case 4: return ldu(sl, base + 768 + r, f32);
        case 5: return ldu(sa, base + 768 + r, f32);
        default: return ldu(sv, base + 768 + r, f32);
    }
}

// Mtmp_i = G_i @ out_w[i]    (block = (i, r2), thread = c; all loads coalesced)
__global__ __launch_bounds__(256) void wcomb1_kernel(
    const void* sl, const void* sa, const void* sv, const void* outw,
    const int* __restrict__ flag, float* __restrict__ Mtmp)
{
    int f32 = *flag;
    int bid = blockIdx.x;
    int i = bid >> 8, r2 = bid & 255;
    int c = threadIdx.x;
    __shared__ float g[256];
    g[c] = gsum_load(i, r2, c, sl, sa, sv, f32);
    __syncthreads();
    float acc = 0.f;
    for (int r = 0; r < 256; ++r)
        acc += g[r] * ldu(outw, (size_t)i * 65536 + r * 256 + c, f32);
    Mtmp[(size_t)i * 65536 + r2 * 256 + c] = acc;
}

// Dstack[(i*256+c)][e] = (final_w @ Mtmp_i)[e][c]   (block = (i, c), thread = e)
// (round-2 proven version)
__global__ __launch_bounds__(256) void wcomb2_kernel(
    const float* __restrict__ Mtmp, const void* finalw,
    const int* __restrict__ flag, float* __restrict__ Dstack)
{
    int f32 = *flag;
    int bid = blockIdx.x;
    int i = bid >> 8, c = bid & 255;
    int e = threadIdx.x;
    __shared__ float mcol[256];
    mcol[e] = Mtmp[(size_t)i * 65536 + e * 256 + c];
    __syncthreads();
    float acc = 0.f;
    #pragma unroll 4
    for (int j = 0; j < 256; ++j)
        acc += ldu(finalw, (size_t)e * 256 + j, f32) * mcol[j];
    Dstack[(size_t)(i * 256 + c) * 256 + e] = acc;
}

// d0 = final_b + final_w @ ((s_l_b+s_a_b+s_v_b) + sum_i G_i @ out_b[i])
// (round-2 proven version)
__global__ __launch_bounds__(256) void bias_kernel(
    const void* sl, const void* sa, const void* sv, const void* outb,
    const void* slb, const void* sab, const void* svb,
    const void* finalw, const void* finalb, const int* __restrict__ flag,
    float* __restrict__ d0)
{
    int f32 = *flag;
    int tid = threadIdx.x;
    __shared__ float c0[256];
    float acc = ldu(slb, tid, f32) + ldu(sab, tid, f32) + ldu(svb, tid, f32);
    for (int i = 0; i < 7; ++i)
        for (int m = 0; m < 256; ++m)
            acc += ldu(outb, i * 256 + m, f32) * gsum_load(i, tid, m, sl, sa, sv, f32);
    c0[tid] = acc;
    __syncthreads();
    float d = ldu(finalb, tid, f32);
    for (int r = 0; r < 256; ++r)
        d += c0[r] * ldu(finalw, (size_t)tid * 256 + r, f32);
    d0[tid] = d;
}

// ---------------------------------------------------------------------------
// Kernel 4: result = O (3072x1792) @ Dstack (1792x256) + d0, skipping zero
// branch K-blocks per row tile's segment(s). Output dtype follows input.
// ---------------------------------------------------------------------------
__global__ __launch_bounds__(256) void final_gemm_kernel(
    const float* __restrict__ O, const float* __restrict__ Dstack,
    const float* __restrict__ d0, const int* __restrict__ flag,
    void* __restrict__ outv)
{
    int f32 = *flag;
    int bx = blockIdx.x;   // col tile 0..3
    int by = blockIdx.y;   // row tile 0..47
    int tid = threadIdx.x;
    int tx = tid & 15, ty = tid >> 4;
    __shared__ float As[64][33];
    __shared__ float Bs[32][65];
    float acc[4][4] = {};

    int t0 = by * 16, t1 = t0 + 15;
    int g0 = (t0 < 300) ? 0 : (t0 < 550 ? 1 : 2);
    int g1 = (t1 < 300) ? 0 : (t1 < 550 ? 1 : 2);
    int activeset = (1 << g0) | (1 << g1);
    const int masks[7] = {7, 3, 5, 6, 1, 2, 4};
    int rowbase = by * 64, colbase = bx * 64;

    for (int i = 0; i < 7; ++i) {
        if (!(masks[i] & activeset)) continue;
        for (int kb = 0; kb < 8; ++kb) {
            int cb = i * 256 + kb * 32;
            __syncthreads();
            #pragma unroll
            for (int l = 0; l < 8; ++l) {
                int idx = l * 256 + tid;
                int r = idx >> 5, c = idx & 31;
                As[r][c] = O[(size_t)(rowbase + r) * 1792 + cb + c];
                int kk = idx >> 6, e2 = idx & 63;
                Bs[kk][e2] = Dstack[(size_t)(cb + kk) * 256 + colbase + e2];
            }
            __syncthreads();
            #pragma unroll 8
            for (int kk = 0; kk < 32; ++kk) {
                float av[4], bv[4];
                #pragma unroll
                for (int u = 0; u < 4; ++u) av[u] = As[ty * 4 + u][kk];
                #pragma unroll
                for (int v = 0; v < 4; ++v) bv[v] = Bs[kk][tx * 4 + v];
                #pragma unroll
                for (int u = 0; u < 4; ++u)
                    #pragma unroll
                    for (int v = 0; v < 4; ++v)
                        acc[u][v] += av[u] * bv[v];
            }
        }
    }
    #pragma unroll
    for (int u = 0; u < 4; ++u)
        #pragma unroll
        for (int v = 0; v < 4; ++v) {
            int r = rowbase + ty * 4 + u, c = colbase + tx * 4 + v;
            float val = acc[u][v] + d0[c];
            if (f32) ((float*)outv)[(size_t)r * 256 + c] = val;
            else ((__hip_bfloat16*)outv)[(size_t)r * 256 + c] = __float2bfloat16(val);
        }
}

// ---------------------------------------------------------------------------
extern "C" void kernel_launch(void* const* d_in, const int* in_sizes, int n_in,
                              void* d_out, int out_size, void* d_ws, size_t ws_size,
                              hipStream_t stream) {
    const void* query     = d_in[0];
    const void* key       = d_in[1];
    const void* value     = d_in[2];
    const void* in_proj_w = d_in[3];
    const void* in_proj_b = d_in[4];
    const void* out_w     = d_in[5];
    const void* out_b     = d_in[6];
    const void* s_l_w     = d_in[7];
    const void* s_l_b     = d_in[8];
    const void* s_a_w     = d_in[9];
    const void* s_a_b     = d_in[10];
    const void* s_v_w     = d_in[11];
    const void* s_v_b     = d_in[12];
    const void* final_w   = d_in[13];
    const void* final_b   = d_in[14];

    float* ws     = (float*)d_ws;
    float* qws    = ws;                 //   786432 f
    float* kws    = ws + 786432;        //   786432 f
    float* vws    = ws + 1572864;       //   786432 f
    float* O      = ws + 2359296;       //  5505024 f (3072 x 1792)
    float* Mtmp   = ws + 7864320;       //   458752 f
    float* Dstack = ws + 8323072;       //   458752 f (1792 x 256)
    float* d0     = ws + 8781824;       //      256 f
    int*   flag   = (int*)(ws + 8782080);  // 1 int (round-2 proven footprint)

    detect_kernel<<<1, 64, 0, stream>>>((const unsigned short*)query, flag);
    qkv_gemm_kernel<<<dim3(12, 48), 256, 0, stream>>>(query, key, value,
                                                      in_proj_w, in_proj_b, flag,
                                                      qws, kws, vws);
    wcomb1_kernel<<<7 * 256, 256, 0, stream>>>(s_l_w, s_a_w, s_v_w, out_w, flag, Mtmp);
    attn_kernel<<<dim3(T, BH), 64, 0, stream>>>(qws, kws, vws, O);
    wcomb2_kernel<<<7 * 256, 256, 0, stream>>>(Mtmp, final_w, flag, Dstack);
    bias_kernel<<<1, 256, 0, stream>>>(s_l_w, s_a_w, s_v_w, out_b,
                                       s_l_b, s_a_b, s_v_b, final_w, final_b,
                                       flag, d0);
    final_gemm_kernel<<<dim3(4, 48), 256, 0, stream>>>(O, Dstack, d0, flag, d_out);
}

// Round 5
// 1128.939 us; speedup vs baseline: 3.2450x; 1.4380x over previous
//
#include <hip/hip_runtime.h>
#include <hip/hip_bf16.h>

#define E 256
#define H 8
#define HD 32
#define T 768
#define B 4
#define BH 32
// segments: L=[0,300), A=[300,550), V=[550,768)

__device__ __forceinline__ float b2f(__hip_bfloat16 x) { return __bfloat162float(x); }

// dtype-agnostic scalar load: f32 ? float : bf16
__device__ __forceinline__ float ldu(const void* p, size_t i, int f32) {
    if (f32) return ((const float*)p)[i];
    return b2f(((const __hip_bfloat16*)p)[i]);
}

// ---------------------------------------------------------------------------
// Kernel 0: input dtype detection (fp32 read as bf16 -> garbage exponents).
// ---------------------------------------------------------------------------
__global__ void detect_kernel(const unsigned short* __restrict__ q,
                              int* __restrict__ flag) {
    if (threadIdx.x == 0 && blockIdx.x == 0) {
        int f32 = 0;
        for (int i = 0; i < 256; ++i) {
            unsigned int bits = ((unsigned int)q[i]) << 16;
            float v = __uint_as_float(bits);
            if (!(v == v) || fabsf(v) > 1e4f) f32 = 1;
        }
        *flag = f32;
    }
}

// ---------------------------------------------------------------------------
// Kernel 1: QKV projection as a tiled GEMM. (proven round-4)
// ---------------------------------------------------------------------------
__global__ __launch_bounds__(256) void qkv_gemm_kernel(
    const void* query, const void* key, const void* value,
    const void* w, const void* bias, const int* __restrict__ flag,
    float* __restrict__ qws, float* __restrict__ kws, float* __restrict__ vws)
{
    int f32 = *flag;
    int bx = blockIdx.x;              // 0..11 col tiles
    int by = blockIdx.y;              // 0..47 row tiles
    int sec = bx >> 2;                // 0=q, 1=k, 2=v
    const void* X = (sec == 0) ? query : (sec == 1) ? key : value;
    int colbase = bx * 64;
    int rowbase = by * 64;
    int tid = threadIdx.x;
    int tx = tid & 15, ty = tid >> 4;
    __shared__ float As[64][33];
    __shared__ float Bs[32][65];
    float acc[4][4] = {};

    for (int kb = 0; kb < 8; ++kb) {
        __syncthreads();
        #pragma unroll
        for (int l = 0; l < 8; ++l) {
            int idx = l * 256 + tid;
            int r = idx >> 5, c = idx & 31;
            As[r][c] = ldu(X, (size_t)(rowbase + r) * 256 + kb * 32 + c, f32);
            int n = idx >> 5, kk = idx & 31;
            Bs[kk][n] = ldu(w, (size_t)(colbase + n) * 256 + kb * 32 + kk, f32);
        }
        __syncthreads();
        #pragma unroll 8
        for (int kk = 0; kk < 32; ++kk) {
            float av[4], bv[4];
            #pragma unroll
            for (int u = 0; u < 4; ++u) av[u] = As[ty * 4 + u][kk];
            #pragma unroll
            for (int v = 0; v < 4; ++v) bv[v] = Bs[kk][tx * 4 + v];
            #pragma unroll
            for (int u = 0; u < 4; ++u)
                #pragma unroll
                for (int v = 0; v < 4; ++v)
                    acc[u][v] += av[u] * bv[v];
        }
    }
    float* dst = (sec == 0) ? qws : (sec == 1) ? kws : vws;
    #pragma unroll
    for (int u = 0; u < 4; ++u)
        #pragma unroll
        for (int v = 0; v < 4; ++v) {
            int r = rowbase + ty * 4 + u;          // t*B + b
            int cg = colbase + tx * 4 + v;         // 0..767
            float val = acc[u][v] + ldu(bias, cg, f32);
            if (sec == 0) val *= 0.17677669529663687f;  // HD^-0.5
            int e_local = cg & 255;
            int h = e_local >> 5, hd = e_local & 31;
            int t = r >> 2, b = r & 3;
            dst[((size_t)((b * H + h) * T + t)) * HD + hd] = val;
        }
}

// ---------------------------------------------------------------------------
// Kernel 2: fused attention core (proven round-2). One wave per (bh, t).
// ---------------------------------------------------------------------------
__global__ __launch_bounds__(64) void attn_kernel(
    const float* __restrict__ qws, const float* __restrict__ kws,
    const float* __restrict__ vws, float* __restrict__ O)
{
    int t = blockIdx.x, bh = blockIdx.y;
    int lane = threadIdx.x;
    __shared__ float q_s[HD];
    __shared__ float e_buf[T];
    __shared__ float S_s[3];
    __shared__ float P_part[2][3][HD];

    if (lane < HD) q_s[lane] = qws[(bh * T + t) * HD + lane];
    __syncthreads();

    float s0 = 0.f, s1 = 0.f, s2 = 0.f;
    for (int s = lane; s < T; s += 64) {
        const float4* kp = (const float4*)(kws + (size_t)(bh * T + s) * HD);
        float sc = 0.f;
        #pragma unroll
        for (int j = 0; j < 8; ++j) {
            float4 kv = kp[j];
            sc += q_s[4 * j] * kv.x + q_s[4 * j + 1] * kv.y +
                  q_s[4 * j + 2] * kv.z + q_s[4 * j + 3] * kv.w;
        }
        float ex = __expf(sc);
        e_buf[s] = ex;
        if (s < 300) s0 += ex; else if (s < 550) s1 += ex; else s2 += ex;
    }
    #pragma unroll
    for (int off = 32; off > 0; off >>= 1) {
        s0 += __shfl_down(s0, off);
        s1 += __shfl_down(s1, off);
        s2 += __shfl_down(s2, off);
    }
    if (lane == 0) { S_s[0] = s0; S_s[1] = s1; S_s[2] = s2; }
    __syncthreads();

    int hd = lane & 31, half = lane >> 5;
    float p0 = 0.f, p1 = 0.f, p2 = 0.f;
    const float* vbase = vws + (size_t)bh * T * HD + hd;
    if (half == 0) {
        for (int s = 0;   s < 300; ++s) p0 += e_buf[s] * vbase[s * HD];
        for (int s = 300; s < 384; ++s) p1 += e_buf[s] * vbase[s * HD];
    } else {
        for (int s = 384; s < 550; ++s) p1 += e_buf[s] * vbase[s * HD];
        for (int s = 550; s < 768; ++s) p2 += e_buf[s] * vbase[s * HD];
    }
    P_part[half][0][hd] = p0;
    P_part[half][1][hd] = p1;
    P_part[half][2][hd] = p2;
    __syncthreads();

    if (lane < 32) {
        float Pv[3], Sv[3];
        Pv[0] = P_part[0][0][hd] + P_part[1][0][hd];
        Pv[1] = P_part[0][1][hd] + P_part[1][1][hd];
        Pv[2] = P_part[0][2][hd] + P_part[1][2][hd];
        Sv[0] = S_s[0]; Sv[1] = S_s[1]; Sv[2] = S_s[2];
        int g = (t < 300) ? 0 : (t < 550 ? 1 : 2);
        int b = bh >> 3, h = bh & 7;
        float* orow = O + (size_t)(t * B + b) * 1792 + h * 32 + hd;
        const int masks[7] = {7, 3, 5, 6, 1, 2, 4};  // LAV,LA,LV,AV,L,A,V
        #pragma unroll
        for (int i = 0; i < 7; ++i) {
            int m = masks[i];
            float num = 0.f, den = 0.f;
            if (m & 1) { num += Pv[0]; den += Sv[0]; }
            if (m & 2) { num += Pv[1]; den += Sv[1]; }
            if (m & 4) { num += Pv[2]; den += Sv[2]; }
            orow[i * 256] = ((m >> g) & 1) ? num / den : 0.f;
        }
    }
}

// ---------------------------------------------------------------------------
// Weight combination: D_i = (final_w @ G_i @ out_w[i])^T stacked as (1792,256).
// ---------------------------------------------------------------------------
__device__ __forceinline__ float gsum_load(int i, int r2, int r,
                                           const void* sl, const void* sa,
                                           const void* sv, int f32)
{
    size_t base = (size_t)r2 * 1024;
    switch (i) {
        case 0: return ldu(sl, base + r, f32) + ldu(sa, base + r, f32) + ldu(sv, base + r, f32);
        case 1: return ldu(sl, base + 256 + r, f32) + ldu(sa, base + 256 + r, f32);
        case 2: return ldu(sl, base + 512 + r, f32) + ldu(sv, base + 256 + r, f32);
        case 3: return ldu(sa, base + 512 + r, f32) + ldu(sv, base + 512 + r, f32);
        case 4: return ldu(sl, base + 768 + r, f32);
        case 5: return ldu(sa, base + 768 + r, f32);
        default: return ldu(sv, base + 768 + r, f32);
    }
}

// Mtmp_i = G_i @ out_w[i]    (proven round-2)
__global__ __launch_bounds__(256) void wcomb1_kernel(
    const void* sl, const void* sa, const void* sv, const void* outw,
    const int* __restrict__ flag, float* __restrict__ Mtmp)
{
    int f32 = *flag;
    int bid = blockIdx.x;
    int i = bid >> 8, r2 = bid & 255;
    int c = threadIdx.x;
    __shared__ float g[256];
    g[c] = gsum_load(i, r2, c, sl, sa, sv, f32);
    __syncthreads();
    float acc = 0.f;
    for (int r = 0; r < 256; ++r)
        acc += g[r] * ldu(outw, (size_t)i * 65536 + r * 256 + c, f32);
    Mtmp[(size_t)i * 65536 + r2 * 256 + c] = acc;
}

// Dstack[(i*256+c)][e] = (final_w @ Mtmp_i)[e][c]   (proven round-2)
__global__ __launch_bounds__(256) void wcomb2_kernel(
    const float* __restrict__ Mtmp, const void* finalw,
    const int* __restrict__ flag, float* __restrict__ Dstack)
{
    int f32 = *flag;
    int bid = blockIdx.x;
    int i = bid >> 8, c = bid & 255;
    int e = threadIdx.x;
    __shared__ float mcol[256];
    mcol[e] = Mtmp[(size_t)i * 65536 + e * 256 + c];
    __syncthreads();
    float acc = 0.f;
    #pragma unroll 4
    for (int j = 0; j < 256; ++j)
        acc += ldu(finalw, (size_t)e * 256 + j, f32) * mcol[j];
    Dstack[(size_t)(i * 256 + c) * 256 + e] = acc;
}

// ---------------------------------------------------------------------------
// Bias path, parallelized. c0 scratch ALIASES the Mtmp region (dead after
// wcomb2; stream order guarantees no hazard). ws footprint unchanged from the
// proven round-4 layout — do NOT grow it (round-3 post-timing corruption).
// ---------------------------------------------------------------------------
// c0[r2] = (s_l_b+s_a_b+s_v_b)[r2] + sum_i (G_i @ out_b[i])[r2]
__global__ __launch_bounds__(256) void bias1_kernel(
    const void* sl, const void* sa, const void* sv, const void* outb,
    const void* slb, const void* sab, const void* svb,
    const int* __restrict__ flag, float* __restrict__ c0)
{
    int f32 = *flag;
    int r2 = blockIdx.x, m = threadIdx.x;
    __shared__ float red[256];
    float acc = 0.f;
    #pragma unroll
    for (int i = 0; i < 7; ++i)
        acc += ldu(outb, i * 256 + m, f32) * gsum_load(i, r2, m, sl, sa, sv, f32);
    red[m] = acc;
    __syncthreads();
    for (int s = 128; s > 0; s >>= 1) {
        if (m < s) red[m] += red[m + s];
        __syncthreads();
    }
    if (m == 0)
        c0[r2] = red[0] + ldu(slb, r2, f32) + ldu(sab, r2, f32) + ldu(svb, r2, f32);
}

// d0[e] = final_b[e] + sum_r c0[r] * finalw[e][r]
__global__ __launch_bounds__(256) void bias2_kernel(
    const float* __restrict__ c0, const void* finalw, const void* finalb,
    const int* __restrict__ flag, float* __restrict__ d0)
{
    int f32 = *flag;
    int e = blockIdx.x, r = threadIdx.x;
    __shared__ float red[256];
    red[r] = c0[r] * ldu(finalw, (size_t)e * 256 + r, f32);
    __syncthreads();
    for (int s = 128; s > 0; s >>= 1) {
        if (r < s) red[r] += red[r + s];
        __syncthreads();
    }
    if (r == 0)
        d0[e] = red[0] + ldu(finalb, e, f32);
}

// ---------------------------------------------------------------------------
// Kernel 4: result = O (3072x1792) @ Dstack (1792x256) + d0 (proven round-2).
// ---------------------------------------------------------------------------
__global__ __launch_bounds__(256) void final_gemm_kernel(
    const float* __restrict__ O, const float* __restrict__ Dstack,
    const float* __restrict__ d0, const int* __restrict__ flag,
    void* __restrict__ outv)
{
    int f32 = *flag;
    int bx = blockIdx.x;   // col tile 0..3
    int by = blockIdx.y;   // row tile 0..47
    int tid = threadIdx.x;
    int tx = tid & 15, ty = tid >> 4;
    __shared__ float As[64][33];
    __shared__ float Bs[32][65];
    float acc[4][4] = {};

    int t0 = by * 16, t1 = t0 + 15;
    int g0 = (t0 < 300) ? 0 : (t0 < 550 ? 1 : 2);
    int g1 = (t1 < 300) ? 0 : (t1 < 550 ? 1 : 2);
    int activeset = (1 << g0) | (1 << g1);
    const int masks[7] = {7, 3, 5, 6, 1, 2, 4};
    int rowbase = by * 64, colbase = bx * 64;

    for (int i = 0; i < 7; ++i) {
        if (!(masks[i] & activeset)) continue;
        for (int kb = 0; kb < 8; ++kb) {
            int cb = i * 256 + kb * 32;
            __syncthreads();
            #pragma unroll
            for (int l = 0; l < 8; ++l) {
                int idx = l * 256 + tid;
                int r = idx >> 5, c = idx & 31;
                As[r][c] = O[(size_t)(rowbase + r) * 1792 + cb + c];
                int kk = idx >> 6, e2 = idx & 63;
                Bs[kk][e2] = Dstack[(size_t)(cb + kk) * 256 + colbase + e2];
            }
            __syncthreads();
            #pragma unroll 8
            for (int kk = 0; kk < 32; ++kk) {
                float av[4], bv[4];
                #pragma unroll
                for (int u = 0; u < 4; ++u) av[u] = As[ty * 4 + u][kk];
                #pragma unroll
                for (int v = 0; v < 4; ++v) bv[v] = Bs[kk][tx * 4 + v];
                #pragma unroll
                for (int u = 0; u < 4; ++u)
                    #pragma unroll
                    for (int v = 0; v < 4; ++v)
                        acc[u][v] += av[u] * bv[v];
            }
        }
    }
    #pragma unroll
    for (int u = 0; u < 4; ++u)
        #pragma unroll
        for (int v = 0; v < 4; ++v) {
            int r = rowbase + ty * 4 + u, c = colbase + tx * 4 + v;
            float val = acc[u][v] + d0[c];
            if (f32) ((float*)outv)[(size_t)r * 256 + c] = val;
            else ((__hip_bfloat16*)outv)[(size_t)r * 256 + c] = __float2bfloat16(val);
        }
}

// ---------------------------------------------------------------------------
extern "C" void kernel_launch(void* const* d_in, const int* in_sizes, int n_in,
                              void* d_out, int out_size, void* d_ws, size_t ws_size,
                              hipStream_t stream) {
    const void* query     = d_in[0];
    const void* key       = d_in[1];
    const void* value     = d_in[2];
    const void* in_proj_w = d_in[3];
    const void* in_proj_b = d_in[4];
    const void* out_w     = d_in[5];
    const void* out_b     = d_in[6];
    const void* s_l_w     = d_in[7];
    const void* s_l_b     = d_in[8];
    const void* s_a_w     = d_in[9];
    const void* s_a_b     = d_in[10];
    const void* s_v_w     = d_in[11];
    const void* s_v_b     = d_in[12];
    const void* final_w   = d_in[13];
    const void* final_b   = d_in[14];

    float* ws     = (float*)d_ws;
    float* qws    = ws;                 //   786432 f
    float* kws    = ws + 786432;        //   786432 f
    float* vws    = ws + 1572864;       //   786432 f
    float* O      = ws + 2359296;       //  5505024 f (3072 x 1792)
    float* Mtmp   = ws + 7864320;       //   458752 f
    float* Dstack = ws + 8323072;       //   458752 f (1792 x 256)
    float* d0     = ws + 8781824;       //      256 f
    int*   flag   = (int*)(ws + 8782080);  // 1 int — proven footprint HIGH-WATER
    float* c0     = Mtmp;               // ALIAS: Mtmp dead after wcomb2

    detect_kernel<<<1, 64, 0, stream>>>((const unsigned short*)query, flag);
    qkv_gemm_kernel<<<dim3(12, 48), 256, 0, stream>>>(query, key, value,
                                                      in_proj_w, in_proj_b, flag,
                                                      qws, kws, vws);
    wcomb1_kernel<<<7 * 256, 256, 0, stream>>>(s_l_w, s_a_w, s_v_w, out_w, flag, Mtmp);
    attn_kernel<<<dim3(T, BH), 64, 0, stream>>>(qws, kws, vws, O);
    wcomb2_kernel<<<7 * 256, 256, 0, stream>>>(Mtmp, final_w, flag, Dstack);
    bias1_kernel<<<256, 256, 0, stream>>>(s_l_w, s_a_w, s_v_w, out_b,
                                          s_l_b, s_a_b, s_v_b, flag, c0);
    bias2_kernel<<<256, 256, 0, stream>>>(c0, final_w, final_b, flag, d0);
    final_gemm_kernel<<<dim3(4, 48), 256, 0, stream>>>(O, Dstack, d0, flag, d_out);
}

// Round 6
// 761.981 us; speedup vs baseline: 4.8077x; 1.4816x over previous
//
#include <hip/hip_runtime.h>
#include <hip/hip_bf16.h>

#define E 256
#define H 8
#define HD 32
#define T 768
#define B 4
#define BH 32
// segments: L=[0,300), A=[300,550), V=[550,768)

__device__ __forceinline__ float b2f(__hip_bfloat16 x) { return __bfloat162float(x); }

// dtype-agnostic scalar load: f32 ? float : bf16
__device__ __forceinline__ float ldu(const void* p, size_t i, int f32) {
    if (f32) return ((const float*)p)[i];
    return b2f(((const __hip_bfloat16*)p)[i]);
}

// ---------------------------------------------------------------------------
// Kernel 0: input dtype detection (fp32 read as bf16 -> garbage exponents).
// ---------------------------------------------------------------------------
__global__ void detect_kernel(const unsigned short* __restrict__ q,
                              int* __restrict__ flag) {
    if (threadIdx.x == 0 && blockIdx.x == 0) {
        int f32 = 0;
        for (int i = 0; i < 256; ++i) {
            unsigned int bits = ((unsigned int)q[i]) << 16;
            float v = __uint_as_float(bits);
            if (!(v == v) || fabsf(v) > 1e4f) f32 = 1;
        }
        *flag = f32;
    }
}

// ---------------------------------------------------------------------------
// Kernel 1: QKV projection as a tiled GEMM. (proven round-4)
// ---------------------------------------------------------------------------
__global__ __launch_bounds__(256) void qkv_gemm_kernel(
    const void* query, const void* key, const void* value,
    const void* w, const void* bias, const int* __restrict__ flag,
    float* __restrict__ qws, float* __restrict__ kws, float* __restrict__ vws)
{
    int f32 = *flag;
    int bx = blockIdx.x;              // 0..11 col tiles
    int by = blockIdx.y;              // 0..47 row tiles
    int sec = bx >> 2;                // 0=q, 1=k, 2=v
    const void* X = (sec == 0) ? query : (sec == 1) ? key : value;
    int colbase = bx * 64;
    int rowbase = by * 64;
    int tid = threadIdx.x;
    int tx = tid & 15, ty = tid >> 4;
    __shared__ float As[64][33];
    __shared__ float Bs[32][65];
    float acc[4][4] = {};

    for (int kb = 0; kb < 8; ++kb) {
        __syncthreads();
        #pragma unroll
        for (int l = 0; l < 8; ++l) {
            int idx = l * 256 + tid;
            int r = idx >> 5, c = idx & 31;
            As[r][c] = ldu(X, (size_t)(rowbase + r) * 256 + kb * 32 + c, f32);
            int n = idx >> 5, kk = idx & 31;
            Bs[kk][n] = ldu(w, (size_t)(colbase + n) * 256 + kb * 32 + kk, f32);
        }
        __syncthreads();
        #pragma unroll 8
        for (int kk = 0; kk < 32; ++kk) {
            float av[4], bv[4];
            #pragma unroll
            for (int u = 0; u < 4; ++u) av[u] = As[ty * 4 + u][kk];
            #pragma unroll
            for (int v = 0; v < 4; ++v) bv[v] = Bs[kk][tx * 4 + v];
            #pragma unroll
            for (int u = 0; u < 4; ++u)
                #pragma unroll
                for (int v = 0; v < 4; ++v)
                    acc[u][v] += av[u] * bv[v];
        }
    }
    float* dst = (sec == 0) ? qws : (sec == 1) ? kws : vws;
    #pragma unroll
    for (int u = 0; u < 4; ++u)
        #pragma unroll
        for (int v = 0; v < 4; ++v) {
            int r = rowbase + ty * 4 + u;          // t*B + b
            int cg = colbase + tx * 4 + v;         // 0..767
            float val = acc[u][v] + ldu(bias, cg, f32);
            if (sec == 0) val *= 0.17677669529663687f;  // HD^-0.5
            int e_local = cg & 255;
            int h = e_local >> 5, hd = e_local & 31;
            int t = r >> 2, b = r & 3;
            dst[((size_t)((b * H + h) * T + t)) * HD + hd] = val;
        }
}

// ---------------------------------------------------------------------------
// Kernel 2 (NEW): t-tiled attention. Block = (t-tile of 64, bh), 256 threads.
// Per 64-wide s-chunk: stage k/v in LDS (reused by all 64 t-rows), compute
// exp(score) tile, accumulate P[seg] += E @ V with segment-uniform subranges.
// S-sums in registers, width-16 shuffle reduction at the end.
// ---------------------------------------------------------------------------
#define PV_BODY(SEG)                                                     \
    {                                                                    \
        float ev0 = e_s[ty * 4 + 0][ss];                                 \
        float ev1 = e_s[ty * 4 + 1][ss];                                 \
        float ev2 = e_s[ty * 4 + 2][ss];                                 \
        float ev3 = e_s[ty * 4 + 3][ss];                                 \
        float v0 = v_s[ss][tx * 2], v1 = v_s[ss][tx * 2 + 1];            \
        pacc[SEG][0][0] += ev0 * v0; pacc[SEG][0][1] += ev0 * v1;        \
        pacc[SEG][1][0] += ev1 * v0; pacc[SEG][1][1] += ev1 * v1;        \
        pacc[SEG][2][0] += ev2 * v0; pacc[SEG][2][1] += ev2 * v1;        \
        pacc[SEG][3][0] += ev3 * v0; pacc[SEG][3][1] += ev3 * v1;        \
    }

__global__ __launch_bounds__(256) void attn_tiled_kernel(
    const float* __restrict__ qws, const float* __restrict__ kws,
    const float* __restrict__ vws, float* __restrict__ O)
{
    int tile = blockIdx.x;       // 0..11
    int bh   = blockIdx.y;       // 0..31
    int t0 = tile * 64;
    int tid = threadIdx.x;
    int tx = tid & 15, ty = tid >> 4;

    __shared__ float q_s[64][33];
    __shared__ float k_s[64][33];
    __shared__ float v_s[64][33];
    __shared__ float e_s[64][65];
    __shared__ float S_s[64][3];

    const float* qbase = qws + ((size_t)bh * T + t0) * HD;
    #pragma unroll
    for (int l = 0; l < 8; ++l) {
        int idx = l * 256 + tid;
        q_s[idx >> 5][idx & 31] = qbase[idx];
    }

    float pacc[3][4][2] = {};   // [seg][u: t-row][w: hd pair]
    float ssum[3][4] = {};      // [seg][u] partial exp-sums over own s-cols

    const float* kbase = kws + (size_t)bh * T * HD;
    const float* vbase = vws + (size_t)bh * T * HD;

    for (int ch = 0; ch < 12; ++ch) {
        int base = ch * 64;
        __syncthreads();    // all waves done reading k_s/v_s/e_s of prev chunk
        #pragma unroll
        for (int l = 0; l < 8; ++l) {
            int idx = l * 256 + tid;
            k_s[idx >> 5][idx & 31] = kbase[(size_t)base * HD + idx];
            v_s[idx >> 5][idx & 31] = vbase[(size_t)base * HD + idx];
        }
        __syncthreads();

        // Phase A: 4x4 score tile, K=32, then exp -> e_s + per-seg sums.
        float sc[4][4] = {};
        #pragma unroll 8
        for (int kk = 0; kk < 32; ++kk) {
            float qv[4], kv[4];
            #pragma unroll
            for (int u = 0; u < 4; ++u) qv[u] = q_s[ty * 4 + u][kk];
            #pragma unroll
            for (int vv = 0; vv < 4; ++vv) kv[vv] = k_s[tx * 4 + vv][kk];
            #pragma unroll
            for (int u = 0; u < 4; ++u)
                #pragma unroll
                for (int vv = 0; vv < 4; ++vv)
                    sc[u][vv] += qv[u] * kv[vv];
        }
        #pragma unroll
        for (int u = 0; u < 4; ++u)
            #pragma unroll
            for (int vv = 0; vv < 4; ++vv) {
                float e = __expf(sc[u][vv]);
                int sg = base + tx * 4 + vv;
                if (sg < 300) ssum[0][u] += e;
                else if (sg < 550) ssum[1][u] += e;
                else ssum[2][u] += e;
                e_s[ty * 4 + u][tx * 4 + vv] = e;
            }
        __syncthreads();

        // Phase B: P[seg] += E @ V, segment subranges (wave-uniform bounds).
        int e0 = min(max(300 - base, 0), 64);
        int e1 = min(max(550 - base, 0), 64);
        for (int ss = 0; ss < e0; ++ss) PV_BODY(0)
        for (int ss = e0; ss < e1; ++ss) PV_BODY(1)
        for (int ss = e1; ss < 64; ++ss) PV_BODY(2)
    }

    // Reduce ssum across tx (16 threads share each t-row group).
    #pragma unroll
    for (int sg = 0; sg < 3; ++sg)
        #pragma unroll
        for (int u = 0; u < 4; ++u) {
            float v = ssum[sg][u];
            v += __shfl_down(v, 8, 16);
            v += __shfl_down(v, 4, 16);
            v += __shfl_down(v, 2, 16);
            v += __shfl_down(v, 1, 16);
            if (tx == 0) S_s[ty * 4 + u][sg] = v;
        }
    __syncthreads();

    // Epilogue: 7 branch outputs for this thread's 4 t-rows x 2 hd.
    int b = bh >> 3, h = bh & 7;
    const int masks[7] = {7, 3, 5, 6, 1, 2, 4};  // LAV,LA,LV,AV,L,A,V
    #pragma unroll
    for (int u = 0; u < 4; ++u) {
        int t = t0 + ty * 4 + u;
        int g = (t < 300) ? 0 : (t < 550 ? 1 : 2);
        float S0 = S_s[ty * 4 + u][0], S1 = S_s[ty * 4 + u][1], S2 = S_s[ty * 4 + u][2];
        float p00 = pacc[0][u][0], p01 = pacc[0][u][1];
        float p10 = pacc[1][u][0], p11 = pacc[1][u][1];
        float p20 = pacc[2][u][0], p21 = pacc[2][u][1];
        float* orow = O + (size_t)(t * B + b) * 1792 + h * 32 + tx * 2;
        #pragma unroll
        for (int i = 0; i < 7; ++i) {
            int m = masks[i];
            float n0 = 0.f, n1 = 0.f, den = 0.f;
            if (m & 1) { n0 += p00; n1 += p01; den += S0; }
            if (m & 2) { n0 += p10; n1 += p11; den += S1; }
            if (m & 4) { n0 += p20; n1 += p21; den += S2; }
            float r = 1.f / den;
            int live = (m >> g) & 1;
            orow[i * 256]     = live ? n0 * r : 0.f;
            orow[i * 256 + 1] = live ? n1 * r : 0.f;
        }
    }
}

// ---------------------------------------------------------------------------
// Weight combination: D_i = (final_w @ G_i @ out_w[i])^T stacked as (1792,256).
// ---------------------------------------------------------------------------
__device__ __forceinline__ float gsum_load(int i, int r2, int r,
                                           const void* sl, const void* sa,
                                           const void* sv, int f32)
{
    size_t base = (size_t)r2 * 1024;
    switch (i) {
        case 0: return ldu(sl, base + r, f32) + ldu(sa, base + r, f32) + ldu(sv, base + r, f32);
        case 1: return ldu(sl, base + 256 + r, f32) + ldu(sa, base + 256 + r, f32);
        case 2: return ldu(sl, base + 512 + r, f32) + ldu(sv, base + 256 + r, f32);
        case 3: return ldu(sa, base + 512 + r, f32) + ldu(sv, base + 512 + r, f32);
        case 4: return ldu(sl, base + 768 + r, f32);
        case 5: return ldu(sa, base + 768 + r, f32);
        default: return ldu(sv, base + 768 + r, f32);
    }
}

// Mtmp_i = G_i @ out_w[i]    (proven round-2)
__global__ __launch_bounds__(256) void wcomb1_kernel(
    const void* sl, const void* sa, const void* sv, const void* outw,
    const int* __restrict__ flag, float* __restrict__ Mtmp)
{
    int f32 = *flag;
    int bid = blockIdx.x;
    int i = bid >> 8, r2 = bid & 255;
    int c = threadIdx.x;
    __shared__ float g[256];
    g[c] = gsum_load(i, r2, c, sl, sa, sv, f32);
    __syncthreads();
    float acc = 0.f;
    for (int r = 0; r < 256; ++r)
        acc += g[r] * ldu(outw, (size_t)i * 65536 + r * 256 + c, f32);
    Mtmp[(size_t)i * 65536 + r2 * 256 + c] = acc;
}

// Dstack[(i*256+c)][e] = (final_w @ Mtmp_i)[e][c]   (proven round-2)
__global__ __launch_bounds__(256) void wcomb2_kernel(
    const float* __restrict__ Mtmp, const void* finalw,
    const int* __restrict__ flag, float* __restrict__ Dstack)
{
    int f32 = *flag;
    int bid = blockIdx.x;
    int i = bid >> 8, c = bid & 255;
    int e = threadIdx.x;
    __shared__ float mcol[256];
    mcol[e] = Mtmp[(size_t)i * 65536 + e * 256 + c];
    __syncthreads();
    float acc = 0.f;
    #pragma unroll 4
    for (int j = 0; j < 256; ++j)
        acc += ldu(finalw, (size_t)e * 256 + j, f32) * mcol[j];
    Dstack[(size_t)(i * 256 + c) * 256 + e] = acc;
}

// ---------------------------------------------------------------------------
// Bias path (proven round-5). c0 ALIASES Mtmp (dead after wcomb2).
// ws footprint unchanged from proven layout — do NOT grow it.
// ---------------------------------------------------------------------------
__global__ __launch_bounds__(256) void bias1_kernel(
    const void* sl, const void* sa, const void* sv, const void* outb,
    const void* slb, const void* sab, const void* svb,
    const int* __restrict__ flag, float* __restrict__ c0)
{
    int f32 = *flag;
    int r2 = blockIdx.x, m = threadIdx.x;
    __shared__ float red[256];
    float acc = 0.f;
    #pragma unroll
    for (int i = 0; i < 7; ++i)
        acc += ldu(outb, i * 256 + m, f32) * gsum_load(i, r2, m, sl, sa, sv, f32);
    red[m] = acc;
    __syncthreads();
    for (int s = 128; s > 0; s >>= 1) {
        if (m < s) red[m] += red[m + s];
        __syncthreads();
    }
    if (m == 0)
        c0[r2] = red[0] + ldu(slb, r2, f32) + ldu(sab, r2, f32) + ldu(svb, r2, f32);
}

__global__ __launch_bounds__(256) void bias2_kernel(
    const float* __restrict__ c0, const void* finalw, const void* finalb,
    const int* __restrict__ flag, float* __restrict__ d0)
{
    int f32 = *flag;
    int e = blockIdx.x, r = threadIdx.x;
    __shared__ float red[256];
    red[r] = c0[r] * ldu(finalw, (size_t)e * 256 + r, f32);
    __syncthreads();
    for (int s = 128; s > 0; s >>= 1) {
        if (r < s) red[r] += red[r + s];
        __syncthreads();
    }
    if (r == 0)
        d0[e] = red[0] + ldu(finalb, e, f32);
}

// ---------------------------------------------------------------------------
// Kernel 4: result = O (3072x1792) @ Dstack (1792x256) + d0 (proven round-2).
// ---------------------------------------------------------------------------
__global__ __launch_bounds__(256) void final_gemm_kernel(
    const float* __restrict__ O, const float* __restrict__ Dstack,
    const float* __restrict__ d0, const int* __restrict__ flag,
    void* __restrict__ outv)
{
    int f32 = *flag;
    int bx = blockIdx.x;   // col tile 0..3
    int by = blockIdx.y;   // row tile 0..47
    int tid = threadIdx.x;
    int tx = tid & 15, ty = tid >> 4;
    __shared__ float As[64][33];
    __shared__ float Bs[32][65];
    float acc[4][4] = {};

    int t0 = by * 16, t1 = t0 + 15;
    int g0 = (t0 < 300) ? 0 : (t0 < 550 ? 1 : 2);
    int g1 = (t1 < 300) ? 0 : (t1 < 550 ? 1 : 2);
    int activeset = (1 << g0) | (1 << g1);
    const int masks[7] = {7, 3, 5, 6, 1, 2, 4};
    int rowbase = by * 64, colbase = bx * 64;

    for (int i = 0; i < 7; ++i) {
        if (!(masks[i] & activeset)) continue;
        for (int kb = 0; kb < 8; ++kb) {
            int cb = i * 256 + kb * 32;
            __syncthreads();
            #pragma unroll
            for (int l = 0; l < 8; ++l) {
                int idx = l * 256 + tid;
                int r = idx >> 5, c = idx & 31;
                As[r][c] = O[(size_t)(rowbase + r) * 1792 + cb + c];
                int kk = idx >> 6, e2 = idx & 63;
                Bs[kk][e2] = Dstack[(size_t)(cb + kk) * 256 + colbase + e2];
            }
            __syncthreads();
            #pragma unroll 8
            for (int kk = 0; kk < 32; ++kk) {
                float av[4], bv[4];
                #pragma unroll
                for (int u = 0; u < 4; ++u) av[u] = As[ty * 4 + u][kk];
                #pragma unroll
                for (int v = 0; v < 4; ++v) bv[v] = Bs[kk][tx * 4 + v];
                #pragma unroll
                for (int u = 0; u < 4; ++u)
                    #pragma unroll
                    for (int v = 0; v < 4; ++v)
                        acc[u][v] += av[u] * bv[v];
            }
        }
    }
    #pragma unroll
    for (int u = 0; u < 4; ++u)
        #pragma unroll
        for (int v = 0; v < 4; ++v) {
            int r = rowbase + ty * 4 + u, c = colbase + tx * 4 + v;
            float val = acc[u][v] + d0[c];
            if (f32) ((float*)outv)[(size_t)r * 256 + c] = val;
            else ((__hip_bfloat16*)outv)[(size_t)r * 256 + c] = __float2bfloat16(val);
        }
}

// ---------------------------------------------------------------------------
extern "C" void kernel_launch(void* const* d_in, const int* in_sizes, int n_in,
                              void* d_out, int out_size, void* d_ws, size_t ws_size,
                              hipStream_t stream) {
    const void* query     = d_in[0];
    const void* key       = d_in[1];
    const void* value     = d_in[2];
    const void* in_proj_w = d_in[3];
    const void* in_proj_b = d_in[4];
    const void* out_w     = d_in[5];
    const void* out_b     = d_in[6];
    const void* s_l_w     = d_in[7];
    const void* s_l_b     = d_in[8];
    const void* s_a_w     = d_in[9];
    const void* s_a_b     = d_in[10];
    const void* s_v_w     = d_in[11];
    const void* s_v_b     = d_in[12];
    const void* final_w   = d_in[13];
    const void* final_b   = d_in[14];

    float* ws     = (float*)d_ws;
    float* qws    = ws;                 //   786432 f
    float* kws    = ws + 786432;        //   786432 f
    float* vws    = ws + 1572864;       //   786432 f
    float* O      = ws + 2359296;       //  5505024 f (3072 x 1792)
    float* Mtmp   = ws + 7864320;       //   458752 f
    float* Dstack = ws + 8323072;       //   458752 f (1792 x 256)
    float* d0     = ws + 8781824;       //      256 f
    int*   flag   = (int*)(ws + 8782080);  // 1 int — proven footprint HIGH-WATER
    float* c0     = Mtmp;               // ALIAS: Mtmp dead after wcomb2

    detect_kernel<<<1, 64, 0, stream>>>((const unsigned short*)query, flag);
    qkv_gemm_kernel<<<dim3(12, 48), 256, 0, stream>>>(query, key, value,
                                                      in_proj_w, in_proj_b, flag,
                                                      qws, kws, vws);
    wcomb1_kernel<<<7 * 256, 256, 0, stream>>>(s_l_w, s_a_w, s_v_w, out_w, flag, Mtmp);
    attn_tiled_kernel<<<dim3(12, 32), 256, 0, stream>>>(qws, kws, vws, O);
    wcomb2_kernel<<<7 * 256, 256, 0, stream>>>(Mtmp, final_w, flag, Dstack);
    bias1_kernel<<<256, 256, 0, stream>>>(s_l_w, s_a_w, s_v_w, out_b,
                                          s_l_b, s_a_b, s_v_b, flag, c0);
    bias2_kernel<<<256, 256, 0, stream>>>(c0, final_w, final_b, flag, d0);
    final_gemm_kernel<<<dim3(4, 48), 256, 0, stream>>>(O, Dstack, d0, flag, d_out);
}

// Round 7
// 556.244 us; speedup vs baseline: 6.5859x; 1.3699x over previous
//
#include <hip/hip_runtime.h>
#include <hip/hip_bf16.h>

#define E 256
#define H 8
#define HD 32
#define T 768
#define B 4
#define BH 32
// segments: L=[0,300), A=[300,550), V=[550,768)

__device__ __forceinline__ float b2f(__hip_bfloat16 x) { return __bfloat162float(x); }

// dtype-agnostic scalar load: f32 ? float : bf16
__device__ __forceinline__ float ldu(const void* p, size_t i, int f32) {
    if (f32) return ((const float*)p)[i];
    return b2f(((const __hip_bfloat16*)p)[i]);
}

// ---------------------------------------------------------------------------
// Kernel 0: input dtype detection (fp32 read as bf16 -> garbage exponents).
// ---------------------------------------------------------------------------
__global__ void detect_kernel(const unsigned short* __restrict__ q,
                              int* __restrict__ flag) {
    if (threadIdx.x == 0 && blockIdx.x == 0) {
        int f32 = 0;
        for (int i = 0; i < 256; ++i) {
            unsigned int bits = ((unsigned int)q[i]) << 16;
            float v = __uint_as_float(bits);
            if (!(v == v) || fabsf(v) > 1e4f) f32 = 1;
        }
        *flag = f32;
    }
}

// ---------------------------------------------------------------------------
// Kernel 1: QKV projection as a tiled GEMM. (proven round-4)
// ---------------------------------------------------------------------------
__global__ __launch_bounds__(256) void qkv_gemm_kernel(
    const void* query, const void* key, const void* value,
    const void* w, const void* bias, const int* __restrict__ flag,
    float* __restrict__ qws, float* __restrict__ kws, float* __restrict__ vws)
{
    int f32 = *flag;
    int bx = blockIdx.x;              // 0..11 col tiles
    int by = blockIdx.y;              // 0..47 row tiles
    int sec = bx >> 2;                // 0=q, 1=k, 2=v
    const void* X = (sec == 0) ? query : (sec == 1) ? key : value;
    int colbase = bx * 64;
    int rowbase = by * 64;
    int tid = threadIdx.x;
    int tx = tid & 15, ty = tid >> 4;
    __shared__ float As[64][33];
    __shared__ float Bs[32][65];
    float acc[4][4] = {};

    for (int kb = 0; kb < 8; ++kb) {
        __syncthreads();
        #pragma unroll
        for (int l = 0; l < 8; ++l) {
            int idx = l * 256 + tid;
            int r = idx >> 5, c = idx & 31;
            As[r][c] = ldu(X, (size_t)(rowbase + r) * 256 + kb * 32 + c, f32);
            int n = idx >> 5, kk = idx & 31;
            Bs[kk][n] = ldu(w, (size_t)(colbase + n) * 256 + kb * 32 + kk, f32);
        }
        __syncthreads();
        #pragma unroll 8
        for (int kk = 0; kk < 32; ++kk) {
            float av[4], bv[4];
            #pragma unroll
            for (int u = 0; u < 4; ++u) av[u] = As[ty * 4 + u][kk];
            #pragma unroll
            for (int v = 0; v < 4; ++v) bv[v] = Bs[kk][tx * 4 + v];
            #pragma unroll
            for (int u = 0; u < 4; ++u)
                #pragma unroll
                for (int v = 0; v < 4; ++v)
                    acc[u][v] += av[u] * bv[v];
        }
    }
    float* dst = (sec == 0) ? qws : (sec == 1) ? kws : vws;
    #pragma unroll
    for (int u = 0; u < 4; ++u)
        #pragma unroll
        for (int v = 0; v < 4; ++v) {
            int r = rowbase + ty * 4 + u;          // t*B + b
            int cg = colbase + tx * 4 + v;         // 0..767
            float val = acc[u][v] + ldu(bias, cg, f32);
            if (sec == 0) val *= 0.17677669529663687f;  // HD^-0.5
            int e_local = cg & 255;
            int h = e_local >> 5, hd = e_local & 31;
            int t = r >> 2, b = r & 3;
            dst[((size_t)((b * H + h) * T + t)) * HD + hd] = val;
        }
}

// ---------------------------------------------------------------------------
// Kernel 2: t-tiled attention (proven round-6). Block = (t-tile of 64, bh).
// ---------------------------------------------------------------------------
#define PV_BODY(SEG)                                                     \
    {                                                                    \
        float ev0 = e_s[ty * 4 + 0][ss];                                 \
        float ev1 = e_s[ty * 4 + 1][ss];                                 \
        float ev2 = e_s[ty * 4 + 2][ss];                                 \
        float ev3 = e_s[ty * 4 + 3][ss];                                 \
        float v0 = v_s[ss][tx * 2], v1 = v_s[ss][tx * 2 + 1];            \
        pacc[SEG][0][0] += ev0 * v0; pacc[SEG][0][1] += ev0 * v1;        \
        pacc[SEG][1][0] += ev1 * v0; pacc[SEG][1][1] += ev1 * v1;        \
        pacc[SEG][2][0] += ev2 * v0; pacc[SEG][2][1] += ev2 * v1;        \
        pacc[SEG][3][0] += ev3 * v0; pacc[SEG][3][1] += ev3 * v1;        \
    }

__global__ __launch_bounds__(256) void attn_tiled_kernel(
    const float* __restrict__ qws, const float* __restrict__ kws,
    const float* __restrict__ vws, float* __restrict__ O)
{
    int tile = blockIdx.x;       // 0..11
    int bh   = blockIdx.y;       // 0..31
    int t0 = tile * 64;
    int tid = threadIdx.x;
    int tx = tid & 15, ty = tid >> 4;

    __shared__ float q_s[64][33];
    __shared__ float k_s[64][33];
    __shared__ float v_s[64][33];
    __shared__ float e_s[64][65];
    __shared__ float S_s[64][3];

    const float* qbase = qws + ((size_t)bh * T + t0) * HD;
    #pragma unroll
    for (int l = 0; l < 8; ++l) {
        int idx = l * 256 + tid;
        q_s[idx >> 5][idx & 31] = qbase[idx];
    }

    float pacc[3][4][2] = {};   // [seg][u: t-row][w: hd pair]
    float ssum[3][4] = {};      // [seg][u] partial exp-sums over own s-cols

    const float* kbase = kws + (size_t)bh * T * HD;
    const float* vbase = vws + (size_t)bh * T * HD;

    for (int ch = 0; ch < 12; ++ch) {
        int base = ch * 64;
        __syncthreads();    // all waves done reading k_s/v_s/e_s of prev chunk
        #pragma unroll
        for (int l = 0; l < 8; ++l) {
            int idx = l * 256 + tid;
            k_s[idx >> 5][idx & 31] = kbase[(size_t)base * HD + idx];
            v_s[idx >> 5][idx & 31] = vbase[(size_t)base * HD + idx];
        }
        __syncthreads();

        // Phase A: 4x4 score tile, K=32, then exp -> e_s + per-seg sums.
        float sc[4][4] = {};
        #pragma unroll 8
        for (int kk = 0; kk < 32; ++kk) {
            float qv[4], kv[4];
            #pragma unroll
            for (int u = 0; u < 4; ++u) qv[u] = q_s[ty * 4 + u][kk];
            #pragma unroll
            for (int vv = 0; vv < 4; ++vv) kv[vv] = k_s[tx * 4 + vv][kk];
            #pragma unroll
            for (int u = 0; u < 4; ++u)
                #pragma unroll
                for (int vv = 0; vv < 4; ++vv)
                    sc[u][vv] += qv[u] * kv[vv];
        }
        #pragma unroll
        for (int u = 0; u < 4; ++u)
            #pragma unroll
            for (int vv = 0; vv < 4; ++vv) {
                float e = __expf(sc[u][vv]);
                int sg = base + tx * 4 + vv;
                if (sg < 300) ssum[0][u] += e;
                else if (sg < 550) ssum[1][u] += e;
                else ssum[2][u] += e;
                e_s[ty * 4 + u][tx * 4 + vv] = e;
            }
        __syncthreads();

        // Phase B: P[seg] += E @ V, segment subranges (wave-uniform bounds).
        int e0 = min(max(300 - base, 0), 64);
        int e1 = min(max(550 - base, 0), 64);
        for (int ss = 0; ss < e0; ++ss) PV_BODY(0)
        for (int ss = e0; ss < e1; ++ss) PV_BODY(1)
        for (int ss = e1; ss < 64; ++ss) PV_BODY(2)
    }

    // Reduce ssum across tx (16 threads share each t-row group).
    #pragma unroll
    for (int sg = 0; sg < 3; ++sg)
        #pragma unroll
        for (int u = 0; u < 4; ++u) {
            float v = ssum[sg][u];
            v += __shfl_down(v, 8, 16);
            v += __shfl_down(v, 4, 16);
            v += __shfl_down(v, 2, 16);
            v += __shfl_down(v, 1, 16);
            if (tx == 0) S_s[ty * 4 + u][sg] = v;
        }
    __syncthreads();

    // Epilogue: 7 branch outputs for this thread's 4 t-rows x 2 hd.
    int b = bh >> 3, h = bh & 7;
    const int masks[7] = {7, 3, 5, 6, 1, 2, 4};  // LAV,LA,LV,AV,L,A,V
    #pragma unroll
    for (int u = 0; u < 4; ++u) {
        int t = t0 + ty * 4 + u;
        int g = (t < 300) ? 0 : (t < 550 ? 1 : 2);
        float S0 = S_s[ty * 4 + u][0], S1 = S_s[ty * 4 + u][1], S2 = S_s[ty * 4 + u][2];
        float p00 = pacc[0][u][0], p01 = pacc[0][u][1];
        float p10 = pacc[1][u][0], p11 = pacc[1][u][1];
        float p20 = pacc[2][u][0], p21 = pacc[2][u][1];
        float* orow = O + (size_t)(t * B + b) * 1792 + h * 32 + tx * 2;
        #pragma unroll
        for (int i = 0; i < 7; ++i) {
            int m = masks[i];
            float n0 = 0.f, n1 = 0.f, den = 0.f;
            if (m & 1) { n0 += p00; n1 += p01; den += S0; }
            if (m & 2) { n0 += p10; n1 += p11; den += S1; }
            if (m & 4) { n0 += p20; n1 += p21; den += S2; }
            float r = 1.f / den;
            int live = (m >> g) & 1;
            orow[i * 256]     = live ? n0 * r : 0.f;
            orow[i * 256 + 1] = live ? n1 * r : 0.f;
        }
    }
}

// ---------------------------------------------------------------------------
// Weight combination: D_i = (final_w @ G_i @ out_w[i])^T stacked as (1792,256).
// ---------------------------------------------------------------------------
__device__ __forceinline__ float gsum_load(int i, int r2, int r,
                                           const void* sl, const void* sa,
                                           const void* sv, int f32)
{
    size_t base = (size_t)r2 * 1024;
    switch (i) {
        case 0: return ldu(sl, base + r, f32) + ldu(sa, base + r, f32) + ldu(sv, base + r, f32);
        case 1: return ldu(sl, base + 256 + r, f32) + ldu(sa, base + 256 + r, f32);
        case 2: return ldu(sl, base + 512 + r, f32) + ldu(sv, base + 256 + r, f32);
        case 3: return ldu(sa, base + 512 + r, f32) + ldu(sv, base + 512 + r, f32);
        case 4: return ldu(sl, base + 768 + r, f32);
        case 5: return ldu(sa, base + 768 + r, f32);
        default: return ldu(sv, base + 768 + r, f32);
    }
}

// Mtmp_i = G_i @ out_w[i]    (proven round-2)
__global__ __launch_bounds__(256) void wcomb1_kernel(
    const void* sl, const void* sa, const void* sv, const void* outw,
    const int* __restrict__ flag, float* __restrict__ Mtmp)
{
    int f32 = *flag;
    int bid = blockIdx.x;
    int i = bid >> 8, r2 = bid & 255;
    int c = threadIdx.x;
    __shared__ float g[256];
    g[c] = gsum_load(i, r2, c, sl, sa, sv, f32);
    __syncthreads();
    float acc = 0.f;
    for (int r = 0; r < 256; ++r)
        acc += g[r] * ldu(outw, (size_t)i * 65536 + r * 256 + c, f32);
    Mtmp[(size_t)i * 65536 + r2 * 256 + c] = acc;
}

// Dstack_i = Mtmp_i^T @ final_w^T as tiled GEMM (re-landed from round 3;
// round-3's failure was the c0 OOB append, not this kernel).
// Dstack[(i*256+c)][e] = sum_j Mtmp[i][j][c] * finalw[e][j]
__global__ __launch_bounds__(256) void wcomb2_gemm_kernel(
    const float* __restrict__ Mtmp, const void* finalw,
    const int* __restrict__ flag, float* __restrict__ Dstack)
{
    int f32 = *flag;
    int bx = blockIdx.x;   // col tile 0..3 (e)
    int by = blockIdx.y;   // row tile 0..3 (c)
    int i  = blockIdx.z;   // branch 0..6
    int tid = threadIdx.x;
    int tx = tid & 15, ty = tid >> 4;
    int colbase = bx * 64, rowbase = by * 64;
    __shared__ float As[64][33];   // Mtmp^T [c][j]
    __shared__ float Bs[32][65];   // finalw^T [j][e]
    float acc[4][4] = {};

    for (int kb = 0; kb < 8; ++kb) {
        __syncthreads();
        #pragma unroll
        for (int l = 0; l < 8; ++l) {
            int idx = l * 256 + tid;
            int r = idx & 63, kk = idx >> 6;      // r contiguous -> coalesced
            As[r][kk] = Mtmp[(size_t)i * 65536 + (kb * 32 + kk) * 256 + rowbase + r];
            int n = idx >> 5, k2 = idx & 31;      // k2 contiguous -> coalesced
            Bs[k2][n] = ldu(finalw, (size_t)(colbase + n) * 256 + kb * 32 + k2, f32);
        }
        __syncthreads();
        #pragma unroll 8
        for (int kk = 0; kk < 32; ++kk) {
            float av[4], bv[4];
            #pragma unroll
            for (int u = 0; u < 4; ++u) av[u] = As[ty * 4 + u][kk];
            #pragma unroll
            for (int v = 0; v < 4; ++v) bv[v] = Bs[kk][tx * 4 + v];
            #pragma unroll
            for (int u = 0; u < 4; ++u)
                #pragma unroll
                for (int v = 0; v < 4; ++v)
                    acc[u][v] += av[u] * bv[v];
        }
    }
    #pragma unroll
    for (int u = 0; u < 4; ++u)
        #pragma unroll
        for (int v = 0; v < 4; ++v) {
            int c = rowbase + ty * 4 + u, e = colbase + tx * 4 + v;
            Dstack[(size_t)(i * 256 + c) * 256 + e] = acc[u][v];
        }
}

// ---------------------------------------------------------------------------
// Bias path (proven round-5). c0 ALIASES Mtmp (dead after wcomb2).
// ws footprint unchanged from proven layout — do NOT grow it.
// ---------------------------------------------------------------------------
__global__ __launch_bounds__(256) void bias1_kernel(
    const void* sl, const void* sa, const void* sv, const void* outb,
    const void* slb, const void* sab, const void* svb,
    const int* __restrict__ flag, float* __restrict__ c0)
{
    int f32 = *flag;
    int r2 = blockIdx.x, m = threadIdx.x;
    __shared__ float red[256];
    float acc = 0.f;
    #pragma unroll
    for (int i = 0; i < 7; ++i)
        acc += ldu(outb, i * 256 + m, f32) * gsum_load(i, r2, m, sl, sa, sv, f32);
    red[m] = acc;
    __syncthreads();
    for (int s = 128; s > 0; s >>= 1) {
        if (m < s) red[m] += red[m + s];
        __syncthreads();
    }
    if (m == 0)
        c0[r2] = red[0] + ldu(slb, r2, f32) + ldu(sab, r2, f32) + ldu(svb, r2, f32);
}

__global__ __launch_bounds__(256) void bias2_kernel(
    const float* __restrict__ c0, const void* finalw, const void* finalb,
    const int* __restrict__ flag, float* __restrict__ d0)
{
    int f32 = *flag;
    int e = blockIdx.x, r = threadIdx.x;
    __shared__ float red[256];
    red[r] = c0[r] * ldu(finalw, (size_t)e * 256 + r, f32);
    __syncthreads();
    for (int s = 128; s > 0; s >>= 1) {
        if (r < s) red[r] += red[r + s];
        __syncthreads();
    }
    if (r == 0)
        d0[e] = red[0] + ldu(finalb, e, f32);
}

// ---------------------------------------------------------------------------
// Kernel 4: result = O (3072x1792) @ Dstack (1792x256) + d0 (proven round-2).
// ---------------------------------------------------------------------------
__global__ __launch_bounds__(256) void final_gemm_kernel(
    const float* __restrict__ O, const float* __restrict__ Dstack,
    const float* __restrict__ d0, const int* __restrict__ flag,
    void* __restrict__ outv)
{
    int f32 = *flag;
    int bx = blockIdx.x;   // col tile 0..3
    int by = blockIdx.y;   // row tile 0..47
    int tid = threadIdx.x;
    int tx = tid & 15, ty = tid >> 4;
    __shared__ float As[64][33];
    __shared__ float Bs[32][65];
    float acc[4][4] = {};

    int t0 = by * 16, t1 = t0 + 15;
    int g0 = (t0 < 300) ? 0 : (t0 < 550 ? 1 : 2);
    int g1 = (t1 < 300) ? 0 : (t1 < 550 ? 1 : 2);
    int activeset = (1 << g0) | (1 << g1);
    const int masks[7] = {7, 3, 5, 6, 1, 2, 4};
    int rowbase = by * 64, colbase = bx * 64;

    for (int i = 0; i < 7; ++i) {
        if (!(masks[i] & activeset)) continue;
        for (int kb = 0; kb < 8; ++kb) {
            int cb = i * 256 + kb * 32;
            __syncthreads();
            #pragma unroll
            for (int l = 0; l < 8; ++l) {
                int idx = l * 256 + tid;
                int r = idx >> 5, c = idx & 31;
                As[r][c] = O[(size_t)(rowbase + r) * 1792 + cb + c];
                int kk = idx >> 6, e2 = idx & 63;
                Bs[kk][e2] = Dstack[(size_t)(cb + kk) * 256 + colbase + e2];
            }
            __syncthreads();
            #pragma unroll 8
            for (int kk = 0; kk < 32; ++kk) {
                float av[4], bv[4];
                #pragma unroll
                for (int u = 0; u < 4; ++u) av[u] = As[ty * 4 + u][kk];
                #pragma unroll
                for (int v = 0; v < 4; ++v) bv[v] = Bs[kk][tx * 4 + v];
                #pragma unroll
                for (int u = 0; u < 4; ++u)
                    #pragma unroll
                    for (int v = 0; v < 4; ++v)
                        acc[u][v] += av[u] * bv[v];
            }
        }
    }
    #pragma unroll
    for (int u = 0; u < 4; ++u)
        #pragma unroll
        for (int v = 0; v < 4; ++v) {
            int r = rowbase + ty * 4 + u, c = colbase + tx * 4 + v;
            float val = acc[u][v] + d0[c];
            if (f32) ((float*)outv)[(size_t)r * 256 + c] = val;
            else ((__hip_bfloat16*)outv)[(size_t)r * 256 + c] = __float2bfloat16(val);
        }
}

// ---------------------------------------------------------------------------
extern "C" void kernel_launch(void* const* d_in, const int* in_sizes, int n_in,
                              void* d_out, int out_size, void* d_ws, size_t ws_size,
                              hipStream_t stream) {
    const void* query     = d_in[0];
    const void* key       = d_in[1];
    const void* value     = d_in[2];
    const void* in_proj_w = d_in[3];
    const void* in_proj_b = d_in[4];
    const void* out_w     = d_in[5];
    const void* out_b     = d_in[6];
    const void* s_l_w     = d_in[7];
    const void* s_l_b     = d_in[8];
    const void* s_a_w     = d_in[9];
    const void* s_a_b     = d_in[10];
    const void* s_v_w     = d_in[11];
    const void* s_v_b     = d_in[12];
    const void* final_w   = d_in[13];
    const void* final_b   = d_in[14];

    float* ws     = (float*)d_ws;
    float* qws    = ws;                 //   786432 f
    float* kws    = ws + 786432;        //   786432 f
    float* vws    = ws + 1572864;       //   786432 f
    float* O      = ws + 2359296;       //  5505024 f (3072 x 1792)
    float* Mtmp   = ws + 7864320;       //   458752 f
    float* Dstack = ws + 8323072;       //   458752 f (1792 x 256)
    float* d0     = ws + 8781824;       //      256 f
    int*   flag   = (int*)(ws + 8782080);  // 1 int — proven footprint HIGH-WATER
    float* c0     = Mtmp;               // ALIAS: Mtmp dead after wcomb2

    detect_kernel<<<1, 64, 0, stream>>>((const unsigned short*)query, flag);
    qkv_gemm_kernel<<<dim3(12, 48), 256, 0, stream>>>(query, key, value,
                                                      in_proj_w, in_proj_b, flag,
                                                      qws, kws, vws);
    wcomb1_kernel<<<7 * 256, 256, 0, stream>>>(s_l_w, s_a_w, s_v_w, out_w, flag, Mtmp);
    attn_tiled_kernel<<<dim3(12, 32), 256, 0, stream>>>(qws, kws, vws, O);
    wcomb2_gemm_kernel<<<dim3(4, 4, 7), 256, 0, stream>>>(Mtmp, final_w, flag, Dstack);
    bias1_kernel<<<256, 256, 0, stream>>>(s_l_w, s_a_w, s_v_w, out_b,
                                          s_l_b, s_a_b, s_v_b, flag, c0);
    bias2_kernel<<<256, 256, 0, stream>>>(c0, final_w, final_b, flag, d0);
    final_gemm_kernel<<<dim3(4, 48), 256, 0, stream>>>(O, Dstack, d0, flag, d_out);
}

// Round 8
// 402.798 us; speedup vs baseline: 9.0949x; 1.3810x over previous
//
#include <hip/hip_runtime.h>
#include <hip/hip_bf16.h>

#define E 256
#define H 8
#define HD 32
#define T 768
#define B 4
#define BH 32
// segments: L=[0,300), A=[300,550), V=[550,768)

__device__ __forceinline__ float b2f(__hip_bfloat16 x) { return __bfloat162float(x); }

// dtype-agnostic scalar load: f32 ? float : bf16
__device__ __forceinline__ float ldu(const void* p, size_t i, int f32) {
    if (f32) return ((const float*)p)[i];
    return b2f(((const __hip_bfloat16*)p)[i]);
}

// ---------------------------------------------------------------------------
// Kernel 0: input dtype detection (fp32 read as bf16 -> garbage exponents).
// ---------------------------------------------------------------------------
__global__ void detect_kernel(const unsigned short* __restrict__ q,
                              int* __restrict__ flag) {
    if (threadIdx.x == 0 && blockIdx.x == 0) {
        int f32 = 0;
        for (int i = 0; i < 256; ++i) {
            unsigned int bits = ((unsigned int)q[i]) << 16;
            float v = __uint_as_float(bits);
            if (!(v == v) || fabsf(v) > 1e4f) f32 = 1;
        }
        *flag = f32;
    }
}

// ---------------------------------------------------------------------------
// Kernel 1: QKV projection as a tiled GEMM. (proven round-4)
// ---------------------------------------------------------------------------
__global__ __launch_bounds__(256) void qkv_gemm_kernel(
    const void* query, const void* key, const void* value,
    const void* w, const void* bias, const int* __restrict__ flag,
    float* __restrict__ qws, float* __restrict__ kws, float* __restrict__ vws)
{
    int f32 = *flag;
    int bx = blockIdx.x;              // 0..11 col tiles
    int by = blockIdx.y;              // 0..47 row tiles
    int sec = bx >> 2;                // 0=q, 1=k, 2=v
    const void* X = (sec == 0) ? query : (sec == 1) ? key : value;
    int colbase = bx * 64;
    int rowbase = by * 64;
    int tid = threadIdx.x;
    int tx = tid & 15, ty = tid >> 4;
    __shared__ float As[64][33];
    __shared__ float Bs[32][65];
    float acc[4][4] = {};

    for (int kb = 0; kb < 8; ++kb) {
        __syncthreads();
        #pragma unroll
        for (int l = 0; l < 8; ++l) {
            int idx = l * 256 + tid;
            int r = idx >> 5, c = idx & 31;
            As[r][c] = ldu(X, (size_t)(rowbase + r) * 256 + kb * 32 + c, f32);
            int n = idx >> 5, kk = idx & 31;
            Bs[kk][n] = ldu(w, (size_t)(colbase + n) * 256 + kb * 32 + kk, f32);
        }
        __syncthreads();
        #pragma unroll 8
        for (int kk = 0; kk < 32; ++kk) {
            float av[4], bv[4];
            #pragma unroll
            for (int u = 0; u < 4; ++u) av[u] = As[ty * 4 + u][kk];
            #pragma unroll
            for (int v = 0; v < 4; ++v) bv[v] = Bs[kk][tx * 4 + v];
            #pragma unroll
            for (int u = 0; u < 4; ++u)
                #pragma unroll
                for (int v = 0; v < 4; ++v)
                    acc[u][v] += av[u] * bv[v];
        }
    }
    float* dst = (sec == 0) ? qws : (sec == 1) ? kws : vws;
    #pragma unroll
    for (int u = 0; u < 4; ++u)
        #pragma unroll
        for (int v = 0; v < 4; ++v) {
            int r = rowbase + ty * 4 + u;          // t*B + b
            int cg = colbase + tx * 4 + v;         // 0..767
            float val = acc[u][v] + ldu(bias, cg, f32);
            if (sec == 0) val *= 0.17677669529663687f;  // HD^-0.5
            int e_local = cg & 255;
            int h = e_local >> 5, hd = e_local & 31;
            int t = r >> 2, b = r & 3;
            dst[((size_t)((b * H + h) * T + t)) * HD + hd] = val;
        }
}

// ---------------------------------------------------------------------------
// Kernel 2: t-tiled attention (proven round-6). Block = (t-tile of 64, bh).
// ---------------------------------------------------------------------------
#define PV_BODY(SEG)                                                     \
    {                                                                    \
        float ev0 = e_s[ty * 4 + 0][ss];                                 \
        float ev1 = e_s[ty * 4 + 1][ss];                                 \
        float ev2 = e_s[ty * 4 + 2][ss];                                 \
        float ev3 = e_s[ty * 4 + 3][ss];                                 \
        float v0 = v_s[ss][tx * 2], v1 = v_s[ss][tx * 2 + 1];            \
        pacc[SEG][0][0] += ev0 * v0; pacc[SEG][0][1] += ev0 * v1;        \
        pacc[SEG][1][0] += ev1 * v0; pacc[SEG][1][1] += ev1 * v1;        \
        pacc[SEG][2][0] += ev2 * v0; pacc[SEG][2][1] += ev2 * v1;        \
        pacc[SEG][3][0] += ev3 * v0; pacc[SEG][3][1] += ev3 * v1;        \
    }

__global__ __launch_bounds__(256) void attn_tiled_kernel(
    const float* __restrict__ qws, const float* __restrict__ kws,
    const float* __restrict__ vws, float* __restrict__ O)
{
    int tile = blockIdx.x;       // 0..11
    int bh   = blockIdx.y;       // 0..31
    int t0 = tile * 64;
    int tid = threadIdx.x;
    int tx = tid & 15, ty = tid >> 4;

    __shared__ float q_s[64][33];
    __shared__ float k_s[64][33];
    __shared__ float v_s[64][33];
    __shared__ float e_s[64][65];
    __shared__ float S_s[64][3];

    const float* qbase = qws + ((size_t)bh * T + t0) * HD;
    #pragma unroll
    for (int l = 0; l < 8; ++l) {
        int idx = l * 256 + tid;
        q_s[idx >> 5][idx & 31] = qbase[idx];
    }

    float pacc[3][4][2] = {};   // [seg][u: t-row][w: hd pair]
    float ssum[3][4] = {};      // [seg][u] partial exp-sums over own s-cols

    const float* kbase = kws + (size_t)bh * T * HD;
    const float* vbase = vws + (size_t)bh * T * HD;

    for (int ch = 0; ch < 12; ++ch) {
        int base = ch * 64;
        __syncthreads();    // all waves done reading k_s/v_s/e_s of prev chunk
        #pragma unroll
        for (int l = 0; l < 8; ++l) {
            int idx = l * 256 + tid;
            k_s[idx >> 5][idx & 31] = kbase[(size_t)base * HD + idx];
            v_s[idx >> 5][idx & 31] = vbase[(size_t)base * HD + idx];
        }
        __syncthreads();

        // Phase A: 4x4 score tile, K=32, then exp -> e_s + per-seg sums.
        float sc[4][4] = {};
        #pragma unroll 8
        for (int kk = 0; kk < 32; ++kk) {
            float qv[4], kv[4];
            #pragma unroll
            for (int u = 0; u < 4; ++u) qv[u] = q_s[ty * 4 + u][kk];
            #pragma unroll
            for (int vv = 0; vv < 4; ++vv) kv[vv] = k_s[tx * 4 + vv][kk];
            #pragma unroll
            for (int u = 0; u < 4; ++u)
                #pragma unroll
                for (int vv = 0; vv < 4; ++vv)
                    sc[u][vv] += qv[u] * kv[vv];
        }
        #pragma unroll
        for (int u = 0; u < 4; ++u)
            #pragma unroll
            for (int vv = 0; vv < 4; ++vv) {
                float e = __expf(sc[u][vv]);
                int sg = base + tx * 4 + vv;
                if (sg < 300) ssum[0][u] += e;
                else if (sg < 550) ssum[1][u] += e;
                else ssum[2][u] += e;
                e_s[ty * 4 + u][tx * 4 + vv] = e;
            }
        __syncthreads();

        // Phase B: P[seg] += E @ V, segment subranges (wave-uniform bounds).
        int e0 = min(max(300 - base, 0), 64);
        int e1 = min(max(550 - base, 0), 64);
        for (int ss = 0; ss < e0; ++ss) PV_BODY(0)
        for (int ss = e0; ss < e1; ++ss) PV_BODY(1)
        for (int ss = e1; ss < 64; ++ss) PV_BODY(2)
    }

    // Reduce ssum across tx (16 threads share each t-row group).
    #pragma unroll
    for (int sg = 0; sg < 3; ++sg)
        #pragma unroll
        for (int u = 0; u < 4; ++u) {
            float v = ssum[sg][u];
            v += __shfl_down(v, 8, 16);
            v += __shfl_down(v, 4, 16);
            v += __shfl_down(v, 2, 16);
            v += __shfl_down(v, 1, 16);
            if (tx == 0) S_s[ty * 4 + u][sg] = v;
        }
    __syncthreads();

    // Epilogue: 7 branch outputs for this thread's 4 t-rows x 2 hd.
    int b = bh >> 3, h = bh & 7;
    const int masks[7] = {7, 3, 5, 6, 1, 2, 4};  // LAV,LA,LV,AV,L,A,V
    #pragma unroll
    for (int u = 0; u < 4; ++u) {
        int t = t0 + ty * 4 + u;
        int g = (t < 300) ? 0 : (t < 550 ? 1 : 2);
        float S0 = S_s[ty * 4 + u][0], S1 = S_s[ty * 4 + u][1], S2 = S_s[ty * 4 + u][2];
        float p00 = pacc[0][u][0], p01 = pacc[0][u][1];
        float p10 = pacc[1][u][0], p11 = pacc[1][u][1];
        float p20 = pacc[2][u][0], p21 = pacc[2][u][1];
        float* orow = O + (size_t)(t * B + b) * 1792 + h * 32 + tx * 2;
        #pragma unroll
        for (int i = 0; i < 7; ++i) {
            int m = masks[i];
            float n0 = 0.f, n1 = 0.f, den = 0.f;
            if (m & 1) { n0 += p00; n1 += p01; den += S0; }
            if (m & 2) { n0 += p10; n1 += p11; den += S1; }
            if (m & 4) { n0 += p20; n1 += p21; den += S2; }
            float r = 1.f / den;
            int live = (m >> g) & 1;
            orow[i * 256]     = live ? n0 * r : 0.f;
            orow[i * 256 + 1] = live ? n1 * r : 0.f;
        }
    }
}

// ---------------------------------------------------------------------------
// Weight combination: D_i = (final_w @ G_i @ out_w[i])^T stacked as (1792,256).
// ---------------------------------------------------------------------------
__device__ __forceinline__ float gsum_load(int i, int r2, int r,
                                           const void* sl, const void* sa,
                                           const void* sv, int f32)
{
    size_t base = (size_t)r2 * 1024;
    switch (i) {
        case 0: return ldu(sl, base + r, f32) + ldu(sa, base + r, f32) + ldu(sv, base + r, f32);
        case 1: return ldu(sl, base + 256 + r, f32) + ldu(sa, base + 256 + r, f32);
        case 2: return ldu(sl, base + 512 + r, f32) + ldu(sv, base + 256 + r, f32);
        case 3: return ldu(sa, base + 512 + r, f32) + ldu(sv, base + 512 + r, f32);
        case 4: return ldu(sl, base + 768 + r, f32);
        case 5: return ldu(sa, base + 768 + r, f32);
        default: return ldu(sv, base + 768 + r, f32);
    }
}

// Mtmp_i = G_i @ out_w[i]    (proven round-2)
__global__ __launch_bounds__(256) void wcomb1_kernel(
    const void* sl, const void* sa, const void* sv, const void* outw,
    const int* __restrict__ flag, float* __restrict__ Mtmp)
{
    int f32 = *flag;
    int bid = blockIdx.x;
    int i = bid >> 8, r2 = bid & 255;
    int c = threadIdx.x;
    __shared__ float g[256];
    g[c] = gsum_load(i, r2, c, sl, sa, sv, f32);
    __syncthreads();
    float acc = 0.f;
    for (int r = 0; r < 256; ++r)
        acc += g[r] * ldu(outw, (size_t)i * 65536 + r * 256 + c, f32);
    Mtmp[(size_t)i * 65536 + r2 * 256 + c] = acc;
}

// Dstack_i = Mtmp_i^T @ final_w^T as tiled GEMM (proven round-7).
// Dstack[(i*256+c)][e] = sum_j Mtmp[i][j][c] * finalw[e][j]
__global__ __launch_bounds__(256) void wcomb2_gemm_kernel(
    const float* __restrict__ Mtmp, const void* finalw,
    const int* __restrict__ flag, float* __restrict__ Dstack)
{
    int f32 = *flag;
    int bx = blockIdx.x;   // col tile 0..3 (e)
    int by = blockIdx.y;   // row tile 0..3 (c)
    int i  = blockIdx.z;   // branch 0..6
    int tid = threadIdx.x;
    int tx = tid & 15, ty = tid >> 4;
    int colbase = bx * 64, rowbase = by * 64;
    __shared__ float As[64][33];   // Mtmp^T [c][j]
    __shared__ float Bs[32][65];   // finalw^T [j][e]
    float acc[4][4] = {};

    for (int kb = 0; kb < 8; ++kb) {
        __syncthreads();
        #pragma unroll
        for (int l = 0; l < 8; ++l) {
            int idx = l * 256 + tid;
            int r = idx & 63, kk = idx >> 6;      // r contiguous -> coalesced
            As[r][kk] = Mtmp[(size_t)i * 65536 + (kb * 32 + kk) * 256 + rowbase + r];
            int n = idx >> 5, k2 = idx & 31;      // k2 contiguous -> coalesced
            Bs[k2][n] = ldu(finalw, (size_t)(colbase + n) * 256 + kb * 32 + k2, f32);
        }
        __syncthreads();
        #pragma unroll 8
        for (int kk = 0; kk < 32; ++kk) {
            float av[4], bv[4];
            #pragma unroll
            for (int u = 0; u < 4; ++u) av[u] = As[ty * 4 + u][kk];
            #pragma unroll
            for (int v = 0; v < 4; ++v) bv[v] = Bs[kk][tx * 4 + v];
            #pragma unroll
            for (int u = 0; u < 4; ++u)
                #pragma unroll
                for (int v = 0; v < 4; ++v)
                    acc[u][v] += av[u] * bv[v];
        }
    }
    #pragma unroll
    for (int u = 0; u < 4; ++u)
        #pragma unroll
        for (int v = 0; v < 4; ++v) {
            int c = rowbase + ty * 4 + u, e = colbase + tx * 4 + v;
            Dstack[(size_t)(i * 256 + c) * 256 + e] = acc[u][v];
        }
}

// ---------------------------------------------------------------------------
// Bias path (proven round-5). c0 ALIASES Mtmp (dead after wcomb2).
// ws footprint unchanged from proven layout — do NOT grow it.
// ---------------------------------------------------------------------------
__global__ __launch_bounds__(256) void bias1_kernel(
    const void* sl, const void* sa, const void* sv, const void* outb,
    const void* slb, const void* sab, const void* svb,
    const int* __restrict__ flag, float* __restrict__ c0)
{
    int f32 = *flag;
    int r2 = blockIdx.x, m = threadIdx.x;
    __shared__ float red[256];
    float acc = 0.f;
    #pragma unroll
    for (int i = 0; i < 7; ++i)
        acc += ldu(outb, i * 256 + m, f32) * gsum_load(i, r2, m, sl, sa, sv, f32);
    red[m] = acc;
    __syncthreads();
    for (int s = 128; s > 0; s >>= 1) {
        if (m < s) red[m] += red[m + s];
        __syncthreads();
    }
    if (m == 0)
        c0[r2] = red[0] + ldu(slb, r2, f32) + ldu(sab, r2, f32) + ldu(svb, r2, f32);
}

__global__ __launch_bounds__(256) void bias2_kernel(
    const float* __restrict__ c0, const void* finalw, const void* finalb,
    const int* __restrict__ flag, float* __restrict__ d0)
{
    int f32 = *flag;
    int e = blockIdx.x, r = threadIdx.x;
    __shared__ float red[256];
    red[r] = c0[r] * ldu(finalw, (size_t)e * 256 + r, f32);
    __syncthreads();
    for (int s = 128; s > 0; s >>= 1) {
        if (r < s) red[r] += red[r + s];
        __syncthreads();
    }
    if (r == 0)
        d0[e] = red[0] + ldu(finalb, e, f32);
}

// ---------------------------------------------------------------------------
// Kernel 4: result = O (3072x1792) @ Dstack (1792x256) + d0.
// RETILED round-8: 32x32 tiles -> grid (8,96) = 768 blocks (~3/CU) to fix the
// 6% occupancy of the 192-block 64x64 version. 2x2 acc/thread, same skeleton.
// ---------------------------------------------------------------------------
__global__ __launch_bounds__(256) void final_gemm_kernel(
    const float* __restrict__ O, const float* __restrict__ Dstack,
    const float* __restrict__ d0, const int* __restrict__ flag,
    void* __restrict__ outv)
{
    int f32 = *flag;
    int bx = blockIdx.x;   // col tile 0..7 (32 cols)
    int by = blockIdx.y;   // row tile 0..95 (32 rows = 8 t values)
    int tid = threadIdx.x;
    int tx = tid & 15, ty = tid >> 4;
    __shared__ float As[32][33];
    __shared__ float Bs[32][33];
    float acc[2][2] = {};

    int t0 = by * 8, t1 = t0 + 7;
    int g0 = (t0 < 300) ? 0 : (t0 < 550 ? 1 : 2);
    int g1 = (t1 < 300) ? 0 : (t1 < 550 ? 1 : 2);
    int activeset = (1 << g0) | (1 << g1);
    const int masks[7] = {7, 3, 5, 6, 1, 2, 4};
    int rowbase = by * 32, colbase = bx * 32;

    for (int i = 0; i < 7; ++i) {
        if (!(masks[i] & activeset)) continue;   // whole O block is zero
        for (int kb = 0; kb < 8; ++kb) {
            int cb = i * 256 + kb * 32;
            __syncthreads();
            #pragma unroll
            for (int l = 0; l < 4; ++l) {
                int idx = l * 256 + tid;
                int r = idx >> 5, c = idx & 31;
                As[r][c] = O[(size_t)(rowbase + r) * 1792 + cb + c];
                Bs[r][c] = Dstack[(size_t)(cb + r) * 256 + colbase + c];
            }
            __syncthreads();
            #pragma unroll 8
            for (int kk = 0; kk < 32; ++kk) {
                float a0 = As[ty * 2][kk], a1 = As[ty * 2 + 1][kk];
                float b0 = Bs[kk][tx * 2], b1 = Bs[kk][tx * 2 + 1];
                acc[0][0] += a0 * b0; acc[0][1] += a0 * b1;
                acc[1][0] += a1 * b0; acc[1][1] += a1 * b1;
            }
        }
    }
    #pragma unroll
    for (int u = 0; u < 2; ++u)
        #pragma unroll
        for (int v = 0; v < 2; ++v) {
            int r = rowbase + ty * 2 + u, c = colbase + tx * 2 + v;
            float val = acc[u][v] + d0[c];
            if (f32) ((float*)outv)[(size_t)r * 256 + c] = val;
            else ((__hip_bfloat16*)outv)[(size_t)r * 256 + c] = __float2bfloat16(val);
        }
}

// ---------------------------------------------------------------------------
extern "C" void kernel_launch(void* const* d_in, const int* in_sizes, int n_in,
                              void* d_out, int out_size, void* d_ws, size_t ws_size,
                              hipStream_t stream) {
    const void* query     = d_in[0];
    const void* key       = d_in[1];
    const void* value     = d_in[2];
    const void* in_proj_w = d_in[3];
    const void* in_proj_b = d_in[4];
    const void* out_w     = d_in[5];
    const void* out_b     = d_in[6];
    const void* s_l_w     = d_in[7];
    const void* s_l_b     = d_in[8];
    const void* s_a_w     = d_in[9];
    const void* s_a_b     = d_in[10];
    const void* s_v_w     = d_in[11];
    const void* s_v_b     = d_in[12];
    const void* final_w   = d_in[13];
    const void* final_b   = d_in[14];

    float* ws     = (float*)d_ws;
    float* qws    = ws;                 //   786432 f
    float* kws    = ws + 786432;        //   786432 f
    float* vws    = ws + 1572864;       //   786432 f
    float* O      = ws + 2359296;       //  5505024 f (3072 x 1792)
    float* Mtmp   = ws + 7864320;       //   458752 f
    float* Dstack = ws + 8323072;       //   458752 f (1792 x 256)
    float* d0     = ws + 8781824;       //      256 f
    int*   flag   = (int*)(ws + 8782080);  // 1 int — proven footprint HIGH-WATER
    float* c0     = Mtmp;               // ALIAS: Mtmp dead after wcomb2

    detect_kernel<<<1, 64, 0, stream>>>((const unsigned short*)query, flag);
    qkv_gemm_kernel<<<dim3(12, 48), 256, 0, stream>>>(query, key, value,
                                                      in_proj_w, in_proj_b, flag,
                                                      qws, kws, vws);
    wcomb1_kernel<<<7 * 256, 256, 0, stream>>>(s_l_w, s_a_w, s_v_w, out_w, flag, Mtmp);
    attn_tiled_kernel<<<dim3(12, 32), 256, 0, stream>>>(qws, kws, vws, O);
    wcomb2_gemm_kernel<<<dim3(4, 4, 7), 256, 0, stream>>>(Mtmp, final_w, flag, Dstack);
    bias1_kernel<<<256, 256, 0, stream>>>(s_l_w, s_a_w, s_v_w, out_b,
                                          s_l_b, s_a_b, s_v_b, flag, c0);
    bias2_kernel<<<256, 256, 0, stream>>>(c0, final_w, final_b, flag, d0);
    final_gemm_kernel<<<dim3(8, 96), 256, 0, stream>>>(O, Dstack, d0, flag, d_out);
}